// Round 1
// baseline (1286.139 us; speedup 1.0000x reference)
//
#include <hip/hip_runtime.h>
#include <hip/hip_bf16.h>
#include <math.h>

// Problem constants (reference: B=2, S=2048, D=1024, H=16, HD=64)
#define B_ 2
#define S_ 2048
#define D_ 1024
#define H_ 16
#define HD_ 64

// ---------------------------------------------------------------------------
// Generic tiled fp32 GEMM with fused bias: C[M,N] = A[M,K] @ B[K,N] + bias[N]
// BM=BN=64, BK=16, 256 threads, 4x4 micro-tile per thread.
// ---------------------------------------------------------------------------
__global__ __launch_bounds__(256) void gemm_bias_kernel(
    const float* __restrict__ A, const float* __restrict__ Bm,
    const float* __restrict__ bias, float* __restrict__ C,
    int M, int N, int K)
{
    __shared__ float As[16][68];   // [k][m], padded: 68 ≡ 4 (mod 32) spreads banks
    __shared__ float Bs[16][68];   // [k][n]

    const int tid = threadIdx.x;
    const int m0 = blockIdx.y * 64;
    const int n0 = blockIdx.x * 64;

    const int tm = (tid >> 4) * 4;   // 0,4,...,60
    const int tn = (tid & 15) * 4;   // 0,4,...,60

    // global load assignments
    const int la_m = tid >> 2;          // 0..63
    const int la_k = (tid & 3) * 4;     // 0,4,8,12
    const int lb_k = tid >> 4;          // 0..15
    const int lb_n = (tid & 15) * 4;    // 0..60

    const float* Aptr = A + (size_t)(m0 + la_m) * K + la_k;
    const float* Bptr = Bm + (size_t)lb_k * N + n0 + lb_n;

    float acc[4][4] = {};

    for (int k0 = 0; k0 < K; k0 += 16) {
        float4 av = *(const float4*)(Aptr + k0);
        float4 bv = *(const float4*)(Bptr + (size_t)k0 * N);
        __syncthreads();                 // protect LDS vs previous iter reads
        As[la_k + 0][la_m] = av.x;
        As[la_k + 1][la_m] = av.y;
        As[la_k + 2][la_m] = av.z;
        As[la_k + 3][la_m] = av.w;
        *(float4*)&Bs[lb_k][lb_n] = bv;
        __syncthreads();
        #pragma unroll
        for (int kk = 0; kk < 16; ++kk) {
            float4 a4 = *(const float4*)&As[kk][tm];
            float4 b4 = *(const float4*)&Bs[kk][tn];
            acc[0][0] += a4.x * b4.x; acc[0][1] += a4.x * b4.y;
            acc[0][2] += a4.x * b4.z; acc[0][3] += a4.x * b4.w;
            acc[1][0] += a4.y * b4.x; acc[1][1] += a4.y * b4.y;
            acc[1][2] += a4.y * b4.z; acc[1][3] += a4.y * b4.w;
            acc[2][0] += a4.z * b4.x; acc[2][1] += a4.z * b4.y;
            acc[2][2] += a4.z * b4.z; acc[2][3] += a4.z * b4.w;
            acc[3][0] += a4.w * b4.x; acc[3][1] += a4.w * b4.y;
            acc[3][2] += a4.w * b4.z; acc[3][3] += a4.w * b4.w;
        }
    }

    float4 bb = *(const float4*)(bias + n0 + tn);
    #pragma unroll
    for (int i = 0; i < 4; ++i) {
        float4 o;
        o.x = acc[i][0] + bb.x;
        o.y = acc[i][1] + bb.y;
        o.z = acc[i][2] + bb.z;
        o.w = acc[i][3] + bb.w;
        *(float4*)(C + (size_t)(m0 + tm + i) * N + n0 + tn) = o;
    }
}

// ---------------------------------------------------------------------------
// Flash-style attention, faithful to the reference mask:
//   masked (strict upper-tri) logits are -9e-13 (≈0), NOT -inf, and still
//   participate in softmax + PV. So we loop over ALL keys.
// One block = one (b,h), 32 queries; K/V tiles of 64 staged in LDS.
// 256 threads: thread = (q_local in [0,32)) * 8 + jd,  jd in [0,8).
//   scores: thread owns keys k = jd + 8*i (strided -> conflict-free b128)
//   PV    : thread owns dims  d = jd*8 .. jd*8+7
// Output written directly in [B,S,D] layout (head-transposed).
// ---------------------------------------------------------------------------
constexpr int QT = 32;
constexpr int KT = 64;

__global__ __launch_bounds__(256) void attn_kernel(
    const float* __restrict__ qkv, float* __restrict__ out)
{
    __shared__ float Qs[QT][68];
    __shared__ float Ks[KT][68];
    __shared__ float Vs[KT][72];
    __shared__ float Ps[QT][65];

    const int tid = threadIdx.x;
    const int bh  = blockIdx.y;
    const int b   = bh / H_;
    const int h   = bh % H_;
    const int q0  = blockIdx.x * QT;

    const int q  = tid >> 3;   // local query row 0..31
    const int jd = tid & 7;    // 0..7
    const int d0 = jd * 8;     // this thread's output-dim block

    // row layout of qkv: [B,S,3D]; this head's q at col h*192, k at +64, v at +128
    const float* qkv_b = qkv + (size_t)b * S_ * (3 * D_) + h * (3 * HD_);

    // ---- load Q tile to LDS (coalesced), then own row to registers ----
    {
        const int qq = tid >> 3;
        const int dd = (tid & 7) * 8;
        const float* src = qkv_b + (size_t)(q0 + qq) * (3 * D_) + dd;
        *(float4*)&Qs[qq][dd]     = *(const float4*)(src);
        *(float4*)&Qs[qq][dd + 4] = *(const float4*)(src + 4);
    }
    __syncthreads();
    float4 qreg[16];
    #pragma unroll
    for (int i = 0; i < 16; ++i) qreg[i] = *(const float4*)&Qs[q][i * 4];

    float m_run = -INFINITY;
    float l_run = 0.f;
    float acc[8] = {};
    const int gq = q0 + q;

    for (int kt = 0; kt < S_; kt += KT) {
        __syncthreads();   // previous iteration's LDS reads done
        // ---- stage K,V tiles ----
        {
            const int kk = tid >> 2;          // 0..63
            const int dd = (tid & 3) * 16;    // 0,16,32,48
            const float* ksrc = qkv_b + (size_t)(kt + kk) * (3 * D_) + HD_ + dd;
            const float* vsrc = ksrc + HD_;
            #pragma unroll
            for (int c = 0; c < 4; ++c)
                *(float4*)&Ks[kk][dd + 4 * c] = *(const float4*)(ksrc + 4 * c);
            #pragma unroll
            for (int c = 0; c < 4; ++c)
                *(float4*)&Vs[kk][dd + 4 * c] = *(const float4*)(vsrc + 4 * c);
        }
        __syncthreads();

        // ---- scores for keys k = jd + 8*i ----
        float p[8];
        float lmax = -INFINITY;
        #pragma unroll
        for (int i = 0; i < 8; ++i) {
            const int k = jd + 8 * i;
            const float4* krow = (const float4*)&Ks[k][0];
            float4 s4 = {0.f, 0.f, 0.f, 0.f};
            #pragma unroll
            for (int dv = 0; dv < 16; ++dv) {
                float4 kv = krow[dv];
                float4 qv = qreg[dv];
                s4.x += qv.x * kv.x;
                s4.y += qv.y * kv.y;
                s4.z += qv.z * kv.z;
                s4.w += qv.w * kv.w;
            }
            float s = ((s4.x + s4.y) + (s4.z + s4.w)) * 0.125f;
            const int gk = kt + k;
            if (gk > gq) s = -9e-13f;      // faithful mask value (not -inf)
            p[i] = s;
            lmax = fmaxf(lmax, s);
        }
        // row max over the 8 lanes of this query (contiguous lanes, width 8)
        #pragma unroll
        for (int off = 1; off < 8; off <<= 1)
            lmax = fmaxf(lmax, __shfl_xor(lmax, off, 8));
        const float m_new = fmaxf(m_run, lmax);
        const float corr  = __expf(m_run - m_new);   // 0 on first tile (-inf - finite)
        float lsum = 0.f;
        #pragma unroll
        for (int i = 0; i < 8; ++i) {
            const float pe = __expf(p[i] - m_new);
            p[i] = pe;
            lsum += pe;
        }
        #pragma unroll
        for (int off = 1; off < 8; off <<= 1)
            lsum += __shfl_xor(lsum, off, 8);
        l_run = l_run * corr + lsum;
        m_run = m_new;
        #pragma unroll
        for (int i = 0; i < 8; ++i) acc[i] *= corr;

        #pragma unroll
        for (int i = 0; i < 8; ++i) Ps[q][jd + 8 * i] = p[i];
        __syncthreads();

        // ---- PV: acc[d] += sum_k P[q][k] * V[k][d0+d] ----
        #pragma unroll 4
        for (int k = 0; k < KT; ++k) {
            const float pv = Ps[q][k];
            float4 v0 = *(const float4*)&Vs[k][d0];
            float4 v1 = *(const float4*)&Vs[k][d0 + 4];
            acc[0] += pv * v0.x; acc[1] += pv * v0.y;
            acc[2] += pv * v0.z; acc[3] += pv * v0.w;
            acc[4] += pv * v1.x; acc[5] += pv * v1.y;
            acc[6] += pv * v1.z; acc[7] += pv * v1.w;
        }
    }

    const float inv = 1.f / l_run;
    float* dst = out + ((size_t)b * S_ + gq) * D_ + h * HD_ + d0;
    float4 o0 = {acc[0] * inv, acc[1] * inv, acc[2] * inv, acc[3] * inv};
    float4 o1 = {acc[4] * inv, acc[5] * inv, acc[6] * inv, acc[7] * inv};
    *(float4*)dst       = o0;
    *(float4*)(dst + 4) = o1;
}

// ---------------------------------------------------------------------------
extern "C" void kernel_launch(void* const* d_in, const int* in_sizes, int n_in,
                              void* d_out, int out_size, void* d_ws, size_t ws_size,
                              hipStream_t stream) {
    const float* x     = (const float*)d_in[0];   // [B,S,D]
    const float* W_qkv = (const float*)d_in[1];   // [D,3D]
    const float* b_qkv = (const float*)d_in[2];   // [3D]
    const float* W_out = (const float*)d_in[3];   // [D,D]
    const float* b_out = (const float*)d_in[4];   // [D]
    float* out = (float*)d_out;                   // [B,S,D]

    // workspace: qkv [B*S, 3D] (50.3 MB) + attn_out [B*S, D] (16.8 MB) = 64 MB
    float* qkv  = (float*)d_ws;
    float* attn = qkv + (size_t)(B_ * S_) * (3 * D_);

    const int M = B_ * S_;       // 4096
    dim3 blk(256);

    // 1) QKV projection: [4096,1024] @ [1024,3072] + bias
    gemm_bias_kernel<<<dim3((3 * D_) / 64, M / 64), blk, 0, stream>>>(
        x, W_qkv, b_qkv, qkv, M, 3 * D_, D_);

    // 2) attention: grid (S/QT, B*H)
    attn_kernel<<<dim3(S_ / QT, B_ * H_), blk, 0, stream>>>(qkv, attn);

    // 3) output projection: [4096,1024] @ [1024,1024] + bias
    gemm_bias_kernel<<<dim3(D_ / 64, M / 64), blk, 0, stream>>>(
        attn, W_out, b_out, out, M, D_, D_);
}

// Round 2
// 734.366 us; speedup vs baseline: 1.7514x; 1.7514x over previous
//
#include <hip/hip_runtime.h>
#include <math.h>

// Problem constants (reference: B=2, S=2048, D=1024, H=16, HD=64)
#define B_ 2
#define S_ 2048
#define D_ 1024
#define H_ 16
#define HD_ 64

typedef short short8 __attribute__((ext_vector_type(8)));
typedef unsigned short ushort8 __attribute__((ext_vector_type(8)));
typedef __bf16 bf16x8 __attribute__((ext_vector_type(8)));
typedef float f32x4 __attribute__((ext_vector_type(4)));

__device__ __forceinline__ unsigned short f2bf(float f) {
    union { float f; unsigned u; } v; v.f = f;
    unsigned r = v.u + 0x7FFFu + ((v.u >> 16) & 1u);   // round-to-nearest-even
    return (unsigned short)(r >> 16);
}
__device__ __forceinline__ float bf2f(unsigned short h) {
    union { unsigned u; float f; } v; v.u = ((unsigned)h) << 16;
    return v.f;
}

// XOR swizzle for [R][64] bf16 tiles (128B rows): spread 16-rows-same-slot reads
// across 8 bank groups. col in elements; only bits 3..5 are XORed -> 16B chunks stay intact.
#define SWZ(row, col) ((((row)) << 6) + (((col)) ^ ((((row)) & 7) << 3)))

__device__ __forceinline__ f32x4 mfma_bf16(bf16x8 a, bf16x8 b, f32x4 c) {
    return __builtin_amdgcn_mfma_f32_16x16x32_bf16(a, b, c, 0, 0, 0);
}

// ---------------------------------------------------------------------------
// fp32 tiled GEMM with fused bias (unchanged from round 1): C = A@B + bias
// ---------------------------------------------------------------------------
__global__ __launch_bounds__(256) void gemm_bias_kernel(
    const float* __restrict__ A, const float* __restrict__ Bm,
    const float* __restrict__ bias, float* __restrict__ C,
    int M, int N, int K)
{
    __shared__ float As[16][68];
    __shared__ float Bs[16][68];

    const int tid = threadIdx.x;
    const int m0 = blockIdx.y * 64;
    const int n0 = blockIdx.x * 64;
    const int tm = (tid >> 4) * 4;
    const int tn = (tid & 15) * 4;
    const int la_m = tid >> 2;
    const int la_k = (tid & 3) * 4;
    const int lb_k = tid >> 4;
    const int lb_n = (tid & 15) * 4;

    const float* Aptr = A + (size_t)(m0 + la_m) * K + la_k;
    const float* Bptr = Bm + (size_t)lb_k * N + n0 + lb_n;

    float acc[4][4] = {};

    for (int k0 = 0; k0 < K; k0 += 16) {
        float4 av = *(const float4*)(Aptr + k0);
        float4 bv = *(const float4*)(Bptr + (size_t)k0 * N);
        __syncthreads();
        As[la_k + 0][la_m] = av.x;
        As[la_k + 1][la_m] = av.y;
        As[la_k + 2][la_m] = av.z;
        As[la_k + 3][la_m] = av.w;
        *(float4*)&Bs[lb_k][lb_n] = bv;
        __syncthreads();
        #pragma unroll
        for (int kk = 0; kk < 16; ++kk) {
            float4 a4 = *(const float4*)&As[kk][tm];
            float4 b4 = *(const float4*)&Bs[kk][tn];
            acc[0][0] += a4.x * b4.x; acc[0][1] += a4.x * b4.y;
            acc[0][2] += a4.x * b4.z; acc[0][3] += a4.x * b4.w;
            acc[1][0] += a4.y * b4.x; acc[1][1] += a4.y * b4.y;
            acc[1][2] += a4.y * b4.z; acc[1][3] += a4.y * b4.w;
            acc[2][0] += a4.z * b4.x; acc[2][1] += a4.z * b4.y;
            acc[2][2] += a4.z * b4.z; acc[2][3] += a4.z * b4.w;
            acc[3][0] += a4.w * b4.x; acc[3][1] += a4.w * b4.y;
            acc[3][2] += a4.w * b4.z; acc[3][3] += a4.w * b4.w;
        }
    }

    float4 bb = *(const float4*)(bias + n0 + tn);
    #pragma unroll
    for (int i = 0; i < 4; ++i) {
        float4 o;
        o.x = acc[i][0] + bb.x;
        o.y = acc[i][1] + bb.y;
        o.z = acc[i][2] + bb.z;
        o.w = acc[i][3] + bb.w;
        *(float4*)(C + (size_t)(m0 + tm + i) * N + n0 + tn) = o;
    }
}

// ---------------------------------------------------------------------------
// MFMA flash attention, split-bf16 (hi+lo) for fp32-level accuracy.
// Block: 256 thr = 4 waves, 64 q-rows (wave w owns q = w*16 + (l&15)).
// KV tiles of 64. Swapped QK^T (mfma(K,Q) -> S^T[key][q]) so softmax state is
// lane-local per q. P via per-wave LDS; swapped PV (mfma(Vt,P) -> O^T[d][q]).
// Mask faithful to reference: strict-upper logits = -9e-13 (participate in softmax).
// ---------------------------------------------------------------------------
__global__ __launch_bounds__(256) void attn_mfma_kernel(
    const float* __restrict__ qkv, float* __restrict__ out)
{
    __shared__ __align__(16) unsigned short Qhi[64 * 64], Qlo[64 * 64];
    __shared__ __align__(16) unsigned short Khi[64 * 64], Klo[64 * 64];
    __shared__ __align__(16) unsigned short Vhi[64 * 64], Vlo[64 * 64]; // transposed [d][key]
    __shared__ __align__(16) unsigned short Ps[4][2][16 * 64];          // per-wave P hi/lo; reused as epilogue fp32 buf

    const int tid = threadIdx.x;
    const int l   = tid & 63;
    const int w   = tid >> 6;
    const int g   = l >> 4;           // octet group 0..3
    const int oct = g * 8;            // k-octet base within a 32-chunk
    const int col = l & 15;           // MFMA 16-dim index
    const int bh  = blockIdx.y;
    const int b   = bh >> 4;          // H_=16
    const int h   = bh & 15;
    const int q0  = blockIdx.x * 64;

    const float* base = qkv + (size_t)b * S_ * (3 * D_) + h * (3 * HD_);

    // ---- stage Q tile [64 q][64 d] hi/lo (swizzled) ----
    {
        const int row = tid >> 2, c0 = (tid & 3) * 16;
        const float* s = base + (size_t)(q0 + row) * (3 * D_) + c0;
        f32x4 fq[4];
        fq[0] = *(const f32x4*)(s);
        fq[1] = *(const f32x4*)(s + 4);
        fq[2] = *(const f32x4*)(s + 8);
        fq[3] = *(const f32x4*)(s + 12);
        #pragma unroll
        for (int j = 0; j < 2; ++j) {
            ushort8 hv, lv;
            #pragma unroll
            for (int i = 0; i < 8; ++i) {
                float x = fq[j * 2 + (i >> 2)][i & 3];
                unsigned short hh = f2bf(x);
                hv[i] = hh;
                lv[i] = f2bf(x - bf2f(hh));
            }
            *(ushort8*)&Qhi[SWZ(row, c0 + 8 * j)] = hv;
            *(ushort8*)&Qlo[SWZ(row, c0 + 8 * j)] = lv;
        }
    }
    __syncthreads();

    // Q fragments (B-operand: lane holds Q[q=col][d = c*32 + oct + j]) - resident all loop
    bf16x8 qh[2], ql[2];
    {
        const int qrow = w * 16 + col;
        qh[0] = *(bf16x8*)&Qhi[SWZ(qrow, oct)];
        qh[1] = *(bf16x8*)&Qhi[SWZ(qrow, 32 + oct)];
        ql[0] = *(bf16x8*)&Qlo[SWZ(qrow, oct)];
        ql[1] = *(bf16x8*)&Qlo[SWZ(qrow, 32 + oct)];
    }

    const int qg = q0 + w * 16 + col;   // this lane's global query index
    float m_run = -INFINITY, l_run = 0.f;
    f32x4 oacc[4] = {};                  // O^T[d = dt*16 + g*4 + r][q = col]

    for (int kt = 0; kt < S_; kt += 64) {
        __syncthreads();   // previous tile's K/Vt fragment reads complete
        // ---- stage K tile [key][d] hi/lo ----
        {
            const int row = tid >> 2, c0 = (tid & 3) * 16;
            const float* s = base + (size_t)(kt + row) * (3 * D_) + HD_ + c0;
            f32x4 fq[4];
            fq[0] = *(const f32x4*)(s);
            fq[1] = *(const f32x4*)(s + 4);
            fq[2] = *(const f32x4*)(s + 8);
            fq[3] = *(const f32x4*)(s + 12);
            #pragma unroll
            for (int j = 0; j < 2; ++j) {
                ushort8 hv, lv;
                #pragma unroll
                for (int i = 0; i < 8; ++i) {
                    float x = fq[j * 2 + (i >> 2)][i & 3];
                    unsigned short hh = f2bf(x);
                    hv[i] = hh;
                    lv[i] = f2bf(x - bf2f(hh));
                }
                *(ushort8*)&Khi[SWZ(row, c0 + 8 * j)] = hv;
                *(ushort8*)&Klo[SWZ(row, c0 + 8 * j)] = lv;
            }
        }
        // ---- stage V transposed: Vt[d][key] hi/lo (2B writes, conflict-free by key=lane) ----
        {
            const int key = tid & 63;
            const int dq  = (tid >> 6) * 4;   // wave w covers d = w*4 + i*16 + c
            const float* s = base + (size_t)(kt + key) * (3 * D_) + 2 * HD_;
            #pragma unroll
            for (int i = 0; i < 4; ++i) {
                f32x4 f = *(const f32x4*)(s + dq + i * 16);
                #pragma unroll
                for (int c = 0; c < 4; ++c) {
                    const int d = dq + i * 16 + c;
                    unsigned short hh = f2bf(f[c]);
                    Vhi[SWZ(d, key)] = hh;
                    Vlo[SWZ(d, key)] = f2bf(f[c] - bf2f(hh));
                }
            }
        }
        __syncthreads();

        // ---- scores: S^T[key][q] = K·Q, 4 key tiles, split-bf16 (3 terms) ----
        f32x4 sacc[4] = {};
        #pragma unroll
        for (int c = 0; c < 2; ++c) {
            #pragma unroll
            for (int t = 0; t < 4; ++t) {
                const int krow = t * 16 + col;
                bf16x8 kh = *(bf16x8*)&Khi[SWZ(krow, c * 32 + oct)];
                bf16x8 kl = *(bf16x8*)&Klo[SWZ(krow, c * 32 + oct)];
                sacc[t] = mfma_bf16(kh, qh[c], sacc[t]);
                sacc[t] = mfma_bf16(kh, ql[c], sacc[t]);
                sacc[t] = mfma_bf16(kl, qh[c], sacc[t]);
            }
        }

        // ---- softmax: lane-local for q=col; keys t*16 + g*4 + r ----
        float p[16];
        float mx = -INFINITY;
        #pragma unroll
        for (int t = 0; t < 4; ++t)
            #pragma unroll
            for (int r = 0; r < 4; ++r) {
                float s = sacc[t][r] * 0.125f;               // 1/sqrt(64)
                if (kt + t * 16 + g * 4 + r > qg) s = -9e-13f; // faithful mask
                p[t * 4 + r] = s;
                mx = fmaxf(mx, s);
            }
        mx = fmaxf(mx, __shfl_xor(mx, 16));
        mx = fmaxf(mx, __shfl_xor(mx, 32));
        const float mnew = fmaxf(m_run, mx);
        const float corr = __expf(m_run - mnew);   // 0 on first tile
        float ls = 0.f;
        #pragma unroll
        for (int t = 0; t < 4; ++t)
            #pragma unroll
            for (int r = 0; r < 4; ++r) {
                float pe = __expf(p[t * 4 + r] - mnew);
                ls += pe;
                unsigned short ph = f2bf(pe);
                const int key = t * 16 + g * 4 + r;
                Ps[w][0][SWZ(col, key)] = ph;
                Ps[w][1][SWZ(col, key)] = f2bf(pe - bf2f(ph));
            }
        ls += __shfl_xor(ls, 16);
        ls += __shfl_xor(ls, 32);
        l_run = l_run * corr + ls;
        m_run = mnew;

        __builtin_amdgcn_wave_barrier();   // pin P writes before P fragment reads (same wave)

        // ---- PV: O^T[d][q] += Vt·P, split-bf16 (3 terms), rescale acc first ----
        #pragma unroll
        for (int t = 0; t < 4; ++t) {
            oacc[t][0] *= corr; oacc[t][1] *= corr;
            oacc[t][2] *= corr; oacc[t][3] *= corr;
        }
        #pragma unroll
        for (int c = 0; c < 2; ++c) {
            bf16x8 pf = *(bf16x8*)&Ps[w][0][SWZ(col, c * 32 + oct)];
            bf16x8 pl = *(bf16x8*)&Ps[w][1][SWZ(col, c * 32 + oct)];
            #pragma unroll
            for (int dt = 0; dt < 4; ++dt) {
                const int drow = dt * 16 + col;
                bf16x8 vh = *(bf16x8*)&Vhi[SWZ(drow, c * 32 + oct)];
                bf16x8 vl = *(bf16x8*)&Vlo[SWZ(drow, c * 32 + oct)];
                oacc[dt] = mfma_bf16(vh, pf, oacc[dt]);
                oacc[dt] = mfma_bf16(vl, pf, oacc[dt]);
                oacc[dt] = mfma_bf16(vh, pl, oacc[dt]);
            }
        }
    }

    // ---- epilogue: normalize, transpose via per-wave LDS, coalesced store ----
    const float inv = 1.f / l_run;
    float* ow = (float*)&Ps[w][0][0];          // 4KB per-wave scratch, use [16][40] fp32
    float* orow = out + ((size_t)b * S_ + q0 + w * 16) * D_ + h * HD_;
    #pragma unroll
    for (int half = 0; half < 2; ++half) {
        __builtin_amdgcn_wave_barrier();
        #pragma unroll
        for (int t = 0; t < 2; ++t)
            #pragma unroll
            for (int r = 0; r < 4; ++r)
                ow[col * 40 + t * 16 + g * 4 + r] = oacc[half * 2 + t][r] * inv;
        __builtin_amdgcn_wave_barrier();
        #pragma unroll
        for (int i = 0; i < 2; ++i) {
            const int q = l >> 2, c4 = (l & 3) + 4 * i;
            f32x4 v = *(f32x4*)&ow[q * 40 + c4 * 4];
            *(f32x4*)(orow + (size_t)q * D_ + half * 32 + c4 * 4) = v;
        }
    }
}

// ---------------------------------------------------------------------------
extern "C" void kernel_launch(void* const* d_in, const int* in_sizes, int n_in,
                              void* d_out, int out_size, void* d_ws, size_t ws_size,
                              hipStream_t stream) {
    const float* x     = (const float*)d_in[0];   // [B,S,D]
    const float* W_qkv = (const float*)d_in[1];   // [D,3D]
    const float* b_qkv = (const float*)d_in[2];   // [3D]
    const float* W_out = (const float*)d_in[3];   // [D,D]
    const float* b_out = (const float*)d_in[4];   // [D]
    float* out = (float*)d_out;                   // [B,S,D]

    float* qkv  = (float*)d_ws;                               // [B*S, 3D]
    float* attn = qkv + (size_t)(B_ * S_) * (3 * D_);          // [B*S, D]

    const int M = B_ * S_;   // 4096
    dim3 blk(256);

    // 1) QKV projection
    gemm_bias_kernel<<<dim3((3 * D_) / 64, M / 64), blk, 0, stream>>>(
        x, W_qkv, b_qkv, qkv, M, 3 * D_, D_);

    // 2) MFMA flash attention
    attn_mfma_kernel<<<dim3(S_ / 64, B_ * H_), blk, 0, stream>>>(qkv, attn);

    // 3) output projection
    gemm_bias_kernel<<<dim3(D_ / 64, M / 64), blk, 0, stream>>>(
        attn, W_out, b_out, out, M, D_, D_);
}

// Round 3
// 351.645 us; speedup vs baseline: 3.6575x; 2.0884x over previous
//
#include <hip/hip_runtime.h>
#include <math.h>

// Problem constants (reference: B=2, S=2048, D=1024, H=16, HD=64)
#define B_ 2
#define S_ 2048
#define D_ 1024
#define H_ 16
#define HD_ 64

typedef unsigned short ushort8 __attribute__((ext_vector_type(8)));
typedef __bf16 bf16x8 __attribute__((ext_vector_type(8)));
typedef float f32x4 __attribute__((ext_vector_type(4)));

__device__ __forceinline__ unsigned short f2bf(float f) {
    union { float f; unsigned u; } v; v.f = f;
    unsigned r = v.u + 0x7FFFu + ((v.u >> 16) & 1u);   // RNE
    return (unsigned short)(r >> 16);
}
__device__ __forceinline__ float bf2f(unsigned short h) {
    union { unsigned u; float f; } v; v.u = ((unsigned)h) << 16;
    return v.f;
}
__device__ __forceinline__ void split2x4(f32x4 a, f32x4 b, ushort8& hi, ushort8& lo) {
    #pragma unroll
    for (int i = 0; i < 4; ++i) {
        unsigned short h = f2bf(a[i]); hi[i] = h; lo[i] = f2bf(a[i] - bf2f(h));
    }
    #pragma unroll
    for (int i = 0; i < 4; ++i) {
        unsigned short h = f2bf(b[i]); hi[4 + i] = h; lo[4 + i] = f2bf(b[i] - bf2f(h));
    }
}

// XOR swizzle for [R][64] bf16 tiles (128B rows): in-row 16B-chunk permute by row&7.
#define SWZ(row, col) ((((row)) << 6) + (((col)) ^ ((((row)) & 7) << 3)))

__device__ __forceinline__ f32x4 mfma_bf16(bf16x8 a, bf16x8 b, f32x4 c) {
    return __builtin_amdgcn_mfma_f32_16x16x32_bf16(a, b, c, 0, 0, 0);
}

typedef __attribute__((address_space(1))) const void gvoid_t;
typedef __attribute__((address_space(3))) void lvoid_t;
__device__ __forceinline__ void gload_lds16(const void* g, void* l) {
    __builtin_amdgcn_global_load_lds((gvoid_t*)g, (lvoid_t*)l, 16, 0, 0);
}

// ---------------------------------------------------------------------------
// conv_rows: fp32 [2048][1024] -> hi/lo bf16, pre-swizzled chunks (key = row&7)
// ---------------------------------------------------------------------------
__global__ __launch_bounds__(256) void conv_rows_kernel(
    const float* __restrict__ in, unsigned short* __restrict__ ohi,
    unsigned short* __restrict__ olo)
{
    const int id = blockIdx.x * 256 + threadIdx.x;   // [0, 2048*128)
    const int r = id >> 7, c = id & 127;
    const float* s = in + (size_t)r * 1024 + c * 8;
    f32x4 v0 = *(const f32x4*)s, v1 = *(const f32x4*)(s + 4);
    ushort8 hi, lo;
    split2x4(v0, v1, hi, lo);
    const int oc = (c & ~7) | ((c ^ r) & 7);
    *(ushort8*)&ohi[(size_t)r * 1024 + oc * 8] = hi;
    *(ushort8*)&olo[(size_t)r * 1024 + oc * 8] = lo;
}

// ---------------------------------------------------------------------------
// conv_wt: W fp32 [1024 k][ldw] -> Wt hi/lo bf16 [N][1024], transposed +
// pre-swizzled (key = n&7). Grid (K/64, N/64).
// ---------------------------------------------------------------------------
__global__ __launch_bounds__(256) void conv_wt_kernel(
    const float* __restrict__ W, int ldw,
    unsigned short* __restrict__ othi, unsigned short* __restrict__ otlo)
{
    __shared__ float T[64][65];
    const int tid = threadIdx.x;
    const int kx = blockIdx.x * 64, ny = blockIdx.y * 64;
    const int kl = tid >> 2, c0 = (tid & 3) * 16;
    const float* s = W + (size_t)(kx + kl) * ldw + ny + c0;
    #pragma unroll
    for (int i = 0; i < 4; ++i) *(f32x4*)&T[kl][c0 + 4 * i] = *(const f32x4*)(s + 4 * i);
    __syncthreads();
    const int nl = tid >> 2, jj = (tid & 3) * 2;
    #pragma unroll
    for (int p = 0; p < 2; ++p) {
        const int j = jj + p;
        f32x4 a, b;
        #pragma unroll
        for (int i = 0; i < 4; ++i) a[i] = T[j * 8 + i][nl];
        #pragma unroll
        for (int i = 0; i < 4; ++i) b[i] = T[j * 8 + 4 + i][nl];
        ushort8 hi, lo;
        split2x4(a, b, hi, lo);
        const int row = ny + nl;
        const int chunk = blockIdx.x * 8 + (j ^ (nl & 7));
        *(ushort8*)&othi[(size_t)row * 1024 + chunk * 8] = hi;
        *(ushort8*)&otlo[(size_t)row * 1024 + chunk * 8] = lo;
    }
}

// ---------------------------------------------------------------------------
// Split-bf16 MFMA GEMM: C[M,N] = A[M,K] @ Bt[N,K]^T + bias.
// A, Bt given hi/lo bf16, globally pre-swizzled. 128x128 tile, BK=64, 4 waves.
// OUTMODE 0: fp32 C.  OUTMODE 1: hi/lo bf16 pre-swizzled (key = m&7).
// ---------------------------------------------------------------------------
template<int OUTMODE>
__global__ __launch_bounds__(256) void gemm_mfma_kernel(
    const unsigned short* __restrict__ Ahi, const unsigned short* __restrict__ Alo,
    const unsigned short* __restrict__ Bthi, const unsigned short* __restrict__ Btlo,
    const float* __restrict__ bias, float* __restrict__ Cf,
    unsigned short* __restrict__ Ohi, unsigned short* __restrict__ Olo,
    int M, int N, int K)
{
    __shared__ __align__(16) unsigned short lds[4 * 8192];   // Ahi|Alo|Bhi|Blo [128][64]
    const int tid = threadIdx.x, lane = tid & 63, w = tid >> 6;
    const int wm = w >> 1, wn = w & 1;
    const int m0 = blockIdx.y * 128, n0 = blockIdx.x * 128;
    const int col = lane & 15, oct = (lane >> 4) * 8;
    const int srow = lane >> 3, scol = (lane & 7) * 8;

    f32x4 acc[4][4] = {};

    for (int kt = 0; kt < K; kt += 64) {
        __syncthreads();
        #pragma unroll
        for (int j = 0; j < 4; ++j) {
            const int cc = w * 4 + j;
            const int row = cc * 8 + srow;
            const size_t aoff = (size_t)(m0 + row) * K + kt + scol;
            const size_t boff = (size_t)(n0 + row) * K + kt + scol;
            gload_lds16(Ahi + aoff,  &lds[0 * 8192 + cc * 512]);
            gload_lds16(Alo + aoff,  &lds[1 * 8192 + cc * 512]);
            gload_lds16(Bthi + boff, &lds[2 * 8192 + cc * 512]);
            gload_lds16(Btlo + boff, &lds[3 * 8192 + cc * 512]);
        }
        __syncthreads();
        #pragma unroll
        for (int kh = 0; kh < 2; ++kh) {
            bf16x8 ah[4], al[4], bh[4], bl[4];
            #pragma unroll
            for (int i = 0; i < 4; ++i) {
                const int ar = wm * 64 + i * 16 + col;
                const int br = wn * 64 + i * 16 + col;
                const int c = kh * 32 + oct;
                ah[i] = *(const bf16x8*)&lds[0 * 8192 + SWZ(ar, c)];
                al[i] = *(const bf16x8*)&lds[1 * 8192 + SWZ(ar, c)];
                bh[i] = *(const bf16x8*)&lds[2 * 8192 + SWZ(br, c)];
                bl[i] = *(const bf16x8*)&lds[3 * 8192 + SWZ(br, c)];
            }
            #pragma unroll
            for (int mi = 0; mi < 4; ++mi)
                #pragma unroll
                for (int nj = 0; nj < 4; ++nj) {
                    acc[mi][nj] = mfma_bf16(ah[mi], bh[nj], acc[mi][nj]);
                    acc[mi][nj] = mfma_bf16(ah[mi], bl[nj], acc[mi][nj]);
                    acc[mi][nj] = mfma_bf16(al[mi], bh[nj], acc[mi][nj]);
                }
        }
    }

    // epilogue: per-wave LDS transpose -> coalesced stores
    __syncthreads();
    float* ow = (float*)&lds[w * 8192];   // [64][64] fp32 per wave (16KB)
    #pragma unroll
    for (int mi = 0; mi < 4; ++mi)
        #pragma unroll
        for (int nj = 0; nj < 4; ++nj)
            #pragma unroll
            for (int r = 0; r < 4; ++r)
                ow[(mi * 16 + (lane >> 4) * 4 + r) * 64 + nj * 16 + col] = acc[mi][nj][r];
    __builtin_amdgcn_wave_barrier();

    const int nc = (lane & 7) * 8;
    const int nabs = n0 + wn * 64 + nc;
    f32x4 bi0 = *(const f32x4*)&bias[nabs];
    f32x4 bi1 = *(const f32x4*)&bias[nabs + 4];
    #pragma unroll
    for (int it = 0; it < 8; ++it) {
        const int rl = it * 8 + (lane >> 3);
        f32x4 v0 = *(const f32x4*)&ow[rl * 64 + nc];
        f32x4 v1 = *(const f32x4*)&ow[rl * 64 + nc + 4];
        v0 += bi0; v1 += bi1;
        const int m = m0 + wm * 64 + rl;
        if (OUTMODE == 0) {
            *(f32x4*)&Cf[(size_t)m * N + nabs] = v0;
            *(f32x4*)&Cf[(size_t)m * N + nabs + 4] = v1;
        } else {
            ushort8 hi, lo;
            split2x4(v0, v1, hi, lo);
            const int chunk = (lane & 7) ^ (m & 7);
            const size_t off = (size_t)m * N + n0 + wn * 64 + chunk * 8;
            *(ushort8*)&Ohi[off] = hi;
            *(ushort8*)&Olo[off] = lo;
        }
    }
}

// ---------------------------------------------------------------------------
// MFMA flash attention (per batch), split-bf16. Inputs/outputs hi/lo bf16
// pre-swizzled. Block: 4 waves, 64 q-rows; KV tiles of 64.
// Mask faithful to reference: strict-upper logits = -9e-13.
// ---------------------------------------------------------------------------
__global__ __launch_bounds__(256) void attn_mfma_kernel(
    const unsigned short* __restrict__ qh_g, const unsigned short* __restrict__ ql_g,
    unsigned short* __restrict__ ohi, unsigned short* __restrict__ olo)
{
    __shared__ __align__(16) unsigned short Qhi[4096], Qlo[4096];
    __shared__ __align__(16) unsigned short Khi[4096], Klo[4096];
    __shared__ __align__(16) unsigned short Vhi[4096], Vlo[4096];   // transposed [d][key]
    __shared__ __align__(16) unsigned short Ps[4][2][1024];

    const int tid = threadIdx.x;
    const int lane = tid & 63;
    const int w   = tid >> 6;
    const int g   = lane >> 4;
    const int oct = g * 8;
    const int col = lane & 15;
    const int h   = blockIdx.y;
    const int q0  = blockIdx.x * 64;

    // ---- stage Q tile via global_load_lds (data pre-swizzled) ----
    #pragma unroll
    for (int j = 0; j < 4; ++j) {
        const int sel = w * 4 + j;                       // 0..15
        const unsigned short* src = (sel & 8) ? ql_g : qh_g;
        unsigned short* dst = (sel & 8) ? Qlo : Qhi;
        const int c = sel & 7;
        const int row = c * 8 + (lane >> 3);
        gload_lds16(src + (size_t)(q0 + row) * 3072 + h * 192 + (lane & 7) * 8,
                    &dst[c * 512]);
    }
    __syncthreads();

    bf16x8 qfh[2], qfl[2];
    {
        const int qrow = w * 16 + col;
        qfh[0] = *(bf16x8*)&Qhi[SWZ(qrow, oct)];
        qfh[1] = *(bf16x8*)&Qhi[SWZ(qrow, 32 + oct)];
        qfl[0] = *(bf16x8*)&Qlo[SWZ(qrow, oct)];
        qfl[1] = *(bf16x8*)&Qlo[SWZ(qrow, 32 + oct)];
    }

    const int qg = q0 + w * 16 + col;
    float m_run = -INFINITY, l_run = 0.f;
    f32x4 oacc[4] = {};

    for (int kt = 0; kt < S_; kt += 64) {
        __syncthreads();
        // ---- stage K via global_load_lds ----
        #pragma unroll
        for (int j = 0; j < 4; ++j) {
            const int sel = w * 4 + j;
            const unsigned short* src = (sel & 8) ? ql_g : qh_g;
            unsigned short* dst = (sel & 8) ? Klo : Khi;
            const int c = sel & 7;
            const int row = c * 8 + (lane >> 3);
            gload_lds16(src + (size_t)(kt + row) * 3072 + h * 192 + 64 + (lane & 7) * 8,
                        &dst[c * 512]);
        }
        // ---- stage V transposed (reg-staged, un-swizzle on read) ----
        {
            const int keyl = tid & 63;
            const int grp = tid >> 6;
            const unsigned short* src = (grp & 2) ? ql_g : qh_g;
            unsigned short* Vt = (grp & 2) ? Vlo : Vhi;
            const unsigned short* vg = src + (size_t)(kt + keyl) * 3072 + h * 192 + 128;
            #pragma unroll
            for (int jj = 0; jj < 4; ++jj) {
                const int j = (grp & 1) * 4 + jj;
                const int phys = j ^ (keyl & 7);
                ushort8 v = *(const ushort8*)&vg[phys * 8];
                #pragma unroll
                for (int e = 0; e < 8; ++e) Vt[SWZ(j * 8 + e, keyl)] = v[e];
            }
        }
        __syncthreads();

        // ---- scores: S^T[key][q] = K·Q (3-term split) ----
        f32x4 sacc[4] = {};
        #pragma unroll
        for (int c = 0; c < 2; ++c) {
            #pragma unroll
            for (int t = 0; t < 4; ++t) {
                const int krow = t * 16 + col;
                bf16x8 kh = *(bf16x8*)&Khi[SWZ(krow, c * 32 + oct)];
                bf16x8 kl = *(bf16x8*)&Klo[SWZ(krow, c * 32 + oct)];
                sacc[t] = mfma_bf16(kh, qfh[c], sacc[t]);
                sacc[t] = mfma_bf16(kh, qfl[c], sacc[t]);
                sacc[t] = mfma_bf16(kl, qfh[c], sacc[t]);
            }
        }

        // ---- softmax (lane-local per q=col) ----
        float p[16];
        float mx = -INFINITY;
        #pragma unroll
        for (int t = 0; t < 4; ++t)
            #pragma unroll
            for (int r = 0; r < 4; ++r) {
                float s = sacc[t][r] * 0.125f;
                if (kt + t * 16 + g * 4 + r > qg) s = -9e-13f;
                p[t * 4 + r] = s;
                mx = fmaxf(mx, s);
            }
        mx = fmaxf(mx, __shfl_xor(mx, 16));
        mx = fmaxf(mx, __shfl_xor(mx, 32));
        const float mnew = fmaxf(m_run, mx);
        const float corr = __expf(m_run - mnew);
        float ls = 0.f;
        #pragma unroll
        for (int t = 0; t < 4; ++t)
            #pragma unroll
            for (int r = 0; r < 4; ++r) {
                float pe = __expf(p[t * 4 + r] - mnew);
                ls += pe;
                unsigned short ph = f2bf(pe);
                const int key = t * 16 + g * 4 + r;
                Ps[w][0][SWZ(col, key)] = ph;
                Ps[w][1][SWZ(col, key)] = f2bf(pe - bf2f(ph));
            }
        ls += __shfl_xor(ls, 16);
        ls += __shfl_xor(ls, 32);
        l_run = l_run * corr + ls;
        m_run = mnew;

        __builtin_amdgcn_wave_barrier();

        // ---- PV: O^T[d][q] += Vt·P (3-term split) ----
        #pragma unroll
        for (int t = 0; t < 4; ++t) {
            oacc[t][0] *= corr; oacc[t][1] *= corr;
            oacc[t][2] *= corr; oacc[t][3] *= corr;
        }
        #pragma unroll
        for (int c = 0; c < 2; ++c) {
            bf16x8 pf = *(bf16x8*)&Ps[w][0][SWZ(col, c * 32 + oct)];
            bf16x8 pl = *(bf16x8*)&Ps[w][1][SWZ(col, c * 32 + oct)];
            #pragma unroll
            for (int dt = 0; dt < 4; ++dt) {
                const int drow = dt * 16 + col;
                bf16x8 vh = *(bf16x8*)&Vhi[SWZ(drow, c * 32 + oct)];
                bf16x8 vl = *(bf16x8*)&Vlo[SWZ(drow, c * 32 + oct)];
                oacc[dt] = mfma_bf16(vh, pf, oacc[dt]);
                oacc[dt] = mfma_bf16(vl, pf, oacc[dt]);
                oacc[dt] = mfma_bf16(vh, pl, oacc[dt]);
            }
        }
    }

    // ---- epilogue: normalize, per-wave transpose, hi/lo pre-swizzled store ----
    const float inv = 1.f / l_run;
    float* ow = (float*)&Ps[w][0][0];      // [16][40] fp32 scratch
    const int q = lane >> 2, j = lane & 3;
    #pragma unroll
    for (int half = 0; half < 2; ++half) {
        __builtin_amdgcn_wave_barrier();
        #pragma unroll
        for (int t = 0; t < 2; ++t)
            #pragma unroll
            for (int r = 0; r < 4; ++r)
                ow[col * 40 + t * 16 + g * 4 + r] = oacc[half * 2 + t][r] * inv;
        __builtin_amdgcn_wave_barrier();
        f32x4 v0 = *(const f32x4*)&ow[q * 40 + j * 8];
        f32x4 v1 = *(const f32x4*)&ow[q * 40 + j * 8 + 4];
        ushort8 hi, lo;
        split2x4(v0, v1, hi, lo);
        const int m = q0 + w * 16 + q;
        const int chunk = (half * 4 + j) ^ (m & 7);
        const size_t off = (size_t)m * 1024 + h * 64 + chunk * 8;
        *(ushort8*)&ohi[off] = hi;
        *(ushort8*)&olo[off] = lo;
    }
}

// ---------------------------------------------------------------------------
extern "C" void kernel_launch(void* const* d_in, const int* in_sizes, int n_in,
                              void* d_out, int out_size, void* d_ws, size_t ws_size,
                              hipStream_t stream) {
    const float* x     = (const float*)d_in[0];   // [B,S,D]
    const float* W_qkv = (const float*)d_in[1];   // [D,3D]
    const float* b_qkv = (const float*)d_in[2];   // [3D]
    const float* W_out = (const float*)d_in[3];   // [D,D]
    const float* b_out = (const float*)d_in[4];   // [D]
    float* out = (float*)d_out;                   // [B,S,D]

    // ws layout (64 MiB total, == proven round-1 footprint):
    unsigned short* ws16 = (unsigned short*)d_ws;
    unsigned short* Wqh = ws16;                               // [3072][1024]
    unsigned short* Wql = Wqh + (size_t)3072 * 1024;
    unsigned short* Woh = Wql + (size_t)3072 * 1024;          // [1024][1024]
    unsigned short* Wol = Woh + (size_t)1024 * 1024;
    unsigned short* Ahi = Wol + (size_t)1024 * 1024;          // [4096][1024] attn out
    unsigned short* Alo = Ahi + (size_t)4096 * 1024;
    unsigned short* Xhi = Alo + (size_t)4096 * 1024;          // [2048][1024] per batch
    unsigned short* Xlo = Xhi + (size_t)2048 * 1024;
    unsigned short* Qh  = Xlo + (size_t)2048 * 1024;          // [2048][3072] per batch
    unsigned short* Ql  = Qh + (size_t)2048 * 3072;

    conv_wt_kernel<<<dim3(16, 48), 256, 0, stream>>>(W_qkv, 3072, Wqh, Wql);
    conv_wt_kernel<<<dim3(16, 16), 256, 0, stream>>>(W_out, 1024, Woh, Wol);

    for (int b = 0; b < 2; ++b) {
        conv_rows_kernel<<<dim3(1024), 256, 0, stream>>>(
            x + (size_t)b * 2048 * 1024, Xhi, Xlo);
        gemm_mfma_kernel<1><<<dim3(24, 16), 256, 0, stream>>>(
            Xhi, Xlo, Wqh, Wql, b_qkv, nullptr, Qh, Ql, 2048, 3072, 1024);
        attn_mfma_kernel<<<dim3(32, 16), 256, 0, stream>>>(
            Qh, Ql, Ahi + (size_t)b * 2048 * 1024, Alo + (size_t)b * 2048 * 1024);
    }

    gemm_mfma_kernel<0><<<dim3(8, 32), 256, 0, stream>>>(
        Ahi, Alo, Woh, Wol, b_out, out, nullptr, nullptr, 4096, 1024, 1024);
}

// Round 4
// 259.893 us; speedup vs baseline: 4.9487x; 1.3530x over previous
//
#include <hip/hip_runtime.h>
#include <math.h>

// Problem constants (reference: B=2, S=2048, D=1024, H=16, HD=64)
#define B_ 2
#define S_ 2048
#define D_ 1024
#define H_ 16
#define HD_ 64

typedef unsigned short ushort8 __attribute__((ext_vector_type(8)));
typedef __bf16 bf16x8 __attribute__((ext_vector_type(8)));
typedef __bf16 bf16x2 __attribute__((ext_vector_type(2)));
typedef float f32x4 __attribute__((ext_vector_type(4)));

__device__ __forceinline__ unsigned short f2bf(float f) {
    union { __bf16 b; unsigned short u; } v;
    v.b = (__bf16)f;                       // native v_cvt, RNE
    return v.u;
}
__device__ __forceinline__ float bf2f(unsigned short u) {
    union { unsigned short u; __bf16 b; } v; v.u = u;
    return (float)v.b;
}
__device__ __forceinline__ void split2x4(f32x4 a, f32x4 b, ushort8& hi, ushort8& lo) {
    #pragma unroll
    for (int i = 0; i < 4; ++i) {
        unsigned short h = f2bf(a[i]); hi[i] = h; lo[i] = f2bf(a[i] - bf2f(h));
    }
    #pragma unroll
    for (int i = 0; i < 4; ++i) {
        unsigned short h = f2bf(b[i]); hi[4 + i] = h; lo[4 + i] = f2bf(b[i] - bf2f(h));
    }
}

// XOR swizzle for [R][64] bf16 tiles (128B rows): in-row 16B-chunk permute by row&7.
#define SWZ(row, col) ((((row)) << 6) + (((col)) ^ ((((row)) & 7) << 3)))

__device__ __forceinline__ f32x4 mfma_bf16(bf16x8 a, bf16x8 b, f32x4 c) {
    return __builtin_amdgcn_mfma_f32_16x16x32_bf16(a, b, c, 0, 0, 0);
}

typedef __attribute__((address_space(1))) const void gvoid_t;
typedef __attribute__((address_space(3))) void lvoid_t;
__device__ __forceinline__ void gload_lds16(const void* g, void* l) {
    __builtin_amdgcn_global_load_lds((gvoid_t*)g, (lvoid_t*)l, 16, 0, 0);
}

// ---------------------------------------------------------------------------
// conv_rows: fp32 [4096][1024] -> hi/lo bf16, pre-swizzled chunks (key = row&7)
// ---------------------------------------------------------------------------
__global__ __launch_bounds__(256) void conv_rows_kernel(
    const float* __restrict__ in, unsigned short* __restrict__ ohi,
    unsigned short* __restrict__ olo)
{
    const int id = blockIdx.x * 256 + threadIdx.x;   // [0, 4096*128)
    const int r = id >> 7, c = id & 127;
    const float* s = in + (size_t)r * 1024 + c * 8;
    f32x4 v0 = *(const f32x4*)s, v1 = *(const f32x4*)(s + 4);
    ushort8 hi, lo;
    split2x4(v0, v1, hi, lo);
    const int oc = (c & ~7) | ((c ^ r) & 7);
    *(ushort8*)&ohi[(size_t)r * 1024 + oc * 8] = hi;
    *(ushort8*)&olo[(size_t)r * 1024 + oc * 8] = lo;
}

// ---------------------------------------------------------------------------
// conv_wt: W fp32 [1024 k][ldw] -> Wt hi/lo bf16 [N][1024], transposed +
// pre-swizzled (key = n&7). Grid (K/64, N/64).
// ---------------------------------------------------------------------------
__global__ __launch_bounds__(256) void conv_wt_kernel(
    const float* __restrict__ W, int ldw,
    unsigned short* __restrict__ othi, unsigned short* __restrict__ otlo)
{
    __shared__ float T[64][65];
    const int tid = threadIdx.x;
    const int kx = blockIdx.x * 64, ny = blockIdx.y * 64;
    const int kl = tid >> 2, c0 = (tid & 3) * 16;
    const float* s = W + (size_t)(kx + kl) * ldw + ny + c0;
    #pragma unroll
    for (int i = 0; i < 4; ++i) *(f32x4*)&T[kl][c0 + 4 * i] = *(const f32x4*)(s + 4 * i);
    __syncthreads();
    const int nl = tid >> 2, jj = (tid & 3) * 2;
    #pragma unroll
    for (int p = 0; p < 2; ++p) {
        const int j = jj + p;
        f32x4 a, b;
        #pragma unroll
        for (int i = 0; i < 4; ++i) a[i] = T[j * 8 + i][nl];
        #pragma unroll
        for (int i = 0; i < 4; ++i) b[i] = T[j * 8 + 4 + i][nl];
        ushort8 hi, lo;
        split2x4(a, b, hi, lo);
        const int row = ny + nl;
        const int chunk = blockIdx.x * 8 + (j ^ (nl & 7));
        *(ushort8*)&othi[(size_t)row * 1024 + chunk * 8] = hi;
        *(ushort8*)&otlo[(size_t)row * 1024 + chunk * 8] = lo;
    }
}

// ---------------------------------------------------------------------------
// Split-bf16 MFMA GEMM: C[M,N] = A[M,K] @ Bt[N,K]^T + bias. (validated r2/r3)
// ---------------------------------------------------------------------------
template<int OUTMODE>
__global__ __launch_bounds__(256) void gemm_mfma_kernel(
    const unsigned short* __restrict__ Ahi, const unsigned short* __restrict__ Alo,
    const unsigned short* __restrict__ Bthi, const unsigned short* __restrict__ Btlo,
    const float* __restrict__ bias, float* __restrict__ Cf,
    unsigned short* __restrict__ Ohi, unsigned short* __restrict__ Olo,
    int M, int N, int K)
{
    __shared__ __align__(16) unsigned short lds[4 * 8192];   // Ahi|Alo|Bhi|Blo [128][64]
    const int tid = threadIdx.x, lane = tid & 63, w = tid >> 6;
    const int wm = w >> 1, wn = w & 1;
    const int m0 = blockIdx.y * 128, n0 = blockIdx.x * 128;
    const int col = lane & 15, oct = (lane >> 4) * 8;
    const int srow = lane >> 3, scol = (lane & 7) * 8;

    f32x4 acc[4][4] = {};

    for (int kt = 0; kt < K; kt += 64) {
        __syncthreads();
        #pragma unroll
        for (int j = 0; j < 4; ++j) {
            const int cc = w * 4 + j;
            const int row = cc * 8 + srow;
            const size_t aoff = (size_t)(m0 + row) * K + kt + scol;
            const size_t boff = (size_t)(n0 + row) * K + kt + scol;
            gload_lds16(Ahi + aoff,  &lds[0 * 8192 + cc * 512]);
            gload_lds16(Alo + aoff,  &lds[1 * 8192 + cc * 512]);
            gload_lds16(Bthi + boff, &lds[2 * 8192 + cc * 512]);
            gload_lds16(Btlo + boff, &lds[3 * 8192 + cc * 512]);
        }
        __syncthreads();
        #pragma unroll
        for (int kh = 0; kh < 2; ++kh) {
            bf16x8 ah[4], al[4], bh[4], bl[4];
            #pragma unroll
            for (int i = 0; i < 4; ++i) {
                const int ar = wm * 64 + i * 16 + col;
                const int br = wn * 64 + i * 16 + col;
                const int c = kh * 32 + oct;
                ah[i] = *(const bf16x8*)&lds[0 * 8192 + SWZ(ar, c)];
                al[i] = *(const bf16x8*)&lds[1 * 8192 + SWZ(ar, c)];
                bh[i] = *(const bf16x8*)&lds[2 * 8192 + SWZ(br, c)];
                bl[i] = *(const bf16x8*)&lds[3 * 8192 + SWZ(br, c)];
            }
            #pragma unroll
            for (int mi = 0; mi < 4; ++mi)
                #pragma unroll
                for (int nj = 0; nj < 4; ++nj) {
                    acc[mi][nj] = mfma_bf16(ah[mi], bh[nj], acc[mi][nj]);
                    acc[mi][nj] = mfma_bf16(ah[mi], bl[nj], acc[mi][nj]);
                    acc[mi][nj] = mfma_bf16(al[mi], bh[nj], acc[mi][nj]);
                }
        }
    }

    __syncthreads();
    float* ow = (float*)&lds[w * 8192];   // [64][64] fp32 per wave
    #pragma unroll
    for (int mi = 0; mi < 4; ++mi)
        #pragma unroll
        for (int nj = 0; nj < 4; ++nj)
            #pragma unroll
            for (int r = 0; r < 4; ++r)
                ow[(mi * 16 + (lane >> 4) * 4 + r) * 64 + nj * 16 + col] = acc[mi][nj][r];
    __builtin_amdgcn_wave_barrier();

    const int nc = (lane & 7) * 8;
    const int nabs = n0 + wn * 64 + nc;
    f32x4 bi0 = *(const f32x4*)&bias[nabs];
    f32x4 bi1 = *(const f32x4*)&bias[nabs + 4];
    #pragma unroll
    for (int it = 0; it < 8; ++it) {
        const int rl = it * 8 + (lane >> 3);
        f32x4 v0 = *(const f32x4*)&ow[rl * 64 + nc];
        f32x4 v1 = *(const f32x4*)&ow[rl * 64 + nc + 4];
        v0 += bi0; v1 += bi1;
        const int m = m0 + wm * 64 + rl;
        if (OUTMODE == 0) {
            *(f32x4*)&Cf[(size_t)m * N + nabs] = v0;
            *(f32x4*)&Cf[(size_t)m * N + nabs + 4] = v1;
        } else {
            ushort8 hi, lo;
            split2x4(v0, v1, hi, lo);
            const int chunk = (lane & 7) ^ (m & 7);
            const size_t off = (size_t)m * N + n0 + wn * 64 + chunk * 8;
            *(ushort8*)&Ohi[off] = hi;
            *(ushort8*)&Olo[off] = lo;
        }
    }
}

// ---------------------------------------------------------------------------
// V suffix tile sums: tsum[h][t][d] = sum_{k in tile t} V[k][d]  (fp32 exact)
// then vsuf[h][t][d] = sum_{t' >= t} tsum  (33 entries, last = 0)
// ---------------------------------------------------------------------------
__global__ __launch_bounds__(256) void vsuf_part_kernel(
    const unsigned short* __restrict__ qh, const unsigned short* __restrict__ ql,
    float* __restrict__ tsum)
{
    const int h = blockIdx.x, tg = blockIdx.y;    // grid (16, 8)
    const int tl = threadIdx.x >> 6, d = threadIdx.x & 63;
    const int t = tg * 4 + tl;
    const int colbase = h * 192 + 128;
    float s = 0.f;
    for (int k = 0; k < 64; ++k) {
        const int row = t * 64 + k;
        const int phys = colbase + (((d >> 3) ^ (row & 7)) << 3) + (d & 7);
        const size_t off = (size_t)row * 3072 + phys;
        s += bf2f(qh[off]) + bf2f(ql[off]);
    }
    tsum[((size_t)h * 32 + t) * 64 + d] = s;
}

__global__ __launch_bounds__(64) void vsuf_scan_kernel(
    const float* __restrict__ tsum, float* __restrict__ vsuf)
{
    const int h = blockIdx.x, d = threadIdx.x;    // 16 blocks x 64 thr
    float acc = 0.f;
    vsuf[((size_t)h * 33 + 32) * 64 + d] = 0.f;
    for (int t = 31; t >= 0; --t) {
        acc += tsum[((size_t)h * 32 + t) * 64 + d];
        vsuf[((size_t)h * 33 + t) * 64 + d] = acc;
    }
}

// ---------------------------------------------------------------------------
// Causal-skip MFMA flash attention.
// Mask semantics: masked logit -9e-13; in fp32 exp(-9e-13 - m) == exp(-m)
// EXACTLY, so upper-triangle tail collapses to vsuf (exact V suffix sums).
// Loop only kt <= q0 (avg 17 of 32 tiles); diagonal tile masked with s=0.0f.
// QK^T: 3-term split-bf16 (scores are exponentiated -> keep accurate).
// PV: 1-term (P-hi x V-hi); dropped lo-terms contribute ~3e-5 each to O.
// Double-buffered K/V, prefetch-before-compute. LDS 56KB, 2 blocks/CU.
// ---------------------------------------------------------------------------
__global__ __launch_bounds__(256, 2) void attn_kernel(
    const unsigned short* __restrict__ qh, const unsigned short* __restrict__ ql,
    const float* __restrict__ vsuf,
    unsigned short* __restrict__ ohi, unsigned short* __restrict__ olo,
    int brow)
{
    __shared__ __align__(16) unsigned short lds[28672];
    // [0,8192): Kbuf0 (hi|lo)   [8192,16384): Kbuf1
    // [16384,20480): Vt0        [20480,24576): Vt1
    // [24576,28672): Ps (4 waves x [16 q][64 key])
    // Q staging aliases [0,8192) before the loop.

    const int tid = threadIdx.x, lane = tid & 63, w = tid >> 6;
    const int g = lane >> 4, oct = g * 8, col = lane & 15;
    const int h = blockIdx.y;
    const int qi = blockIdx.x;
    const int q0idx = (qi & 1) ? (31 - (qi >> 1)) : (qi >> 1);  // balance pairing
    const int q0 = q0idx * 64;
    const int ntiles = q0idx + 1;
    const int kp = tid & 31, dg = tid >> 5;   // V staging roles

    // ---- stage Q tile (pre-swizzled global -> linear LDS) ----
    #pragma unroll
    for (int j = 0; j < 4; ++j) {
        const int cc = w * 4 + j;
        const unsigned short* src = (cc < 8) ? qh : ql;
        const int c7 = cc & 7;
        const int row = q0 + c7 * 8 + (lane >> 3);
        gload_lds16(src + (size_t)row * 3072 + h * 192 + (lane & 7) * 8,
                    &lds[(cc < 8 ? 0 : 4096) + c7 * 512]);
    }
    __syncthreads();
    bf16x8 qfh[2], qfl[2];
    {
        const int qrow = w * 16 + col;
        qfh[0] = *(const bf16x8*)&lds[SWZ(qrow, oct)];
        qfh[1] = *(const bf16x8*)&lds[SWZ(qrow, 32 + oct)];
        qfl[0] = *(const bf16x8*)&lds[4096 + SWZ(qrow, oct)];
        qfl[1] = *(const bf16x8*)&lds[4096 + SWZ(qrow, 32 + oct)];
    }
    __syncthreads();

    const int qg = q0 + w * 16 + col;
    float m_run = 0.f, l_run = 0.f;   // m init 0: masked weight exp(0-m), exact
    f32x4 oacc[4] = {};

    auto stageK = [&](int bufi, int kt) {
        #pragma unroll
        for (int j = 0; j < 4; ++j) {
            const int cc = w * 4 + j;
            const unsigned short* src = (cc < 8) ? qh : ql;
            const int c7 = cc & 7;
            const int row = kt + c7 * 8 + (lane >> 3);
            gload_lds16(src + (size_t)row * 3072 + h * 192 + 64 + (lane & 7) * 8,
                        &lds[bufi * 8192 + (cc < 8 ? 0 : 4096) + c7 * 512]);
        }
    };
    auto vload = [&](int kt, bf16x8& vA, bf16x8& vB) {
        const int r0 = kt + 2 * kp, r1 = r0 + 1;
        const int pA = dg ^ (r0 & 7), pB = dg ^ (r1 & 7);
        vA = *(const bf16x8*)&qh[(size_t)r0 * 3072 + h * 192 + 128 + pA * 8];
        vB = *(const bf16x8*)&qh[(size_t)r1 * 3072 + h * 192 + 128 + pB * 8];
    };
    auto vwrite = [&](int bufi, bf16x8 vA, bf16x8 vB) {
        unsigned short* vt = &lds[16384 + bufi * 4096];
        #pragma unroll
        for (int e = 0; e < 8; ++e) {
            const int d = dg * 8 + e;
            bf16x2 pr; pr[0] = vA[e]; pr[1] = vB[e];
            *(bf16x2*)&vt[SWZ(d, 2 * kp)] = pr;   // even col -> 4B aligned
        }
    };

    // prologue: tile 0
    {
        stageK(0, 0);
        bf16x8 vA, vB;
        vload(0, vA, vB);
        vwrite(0, vA, vB);
    }
    __syncthreads();

    int cur = 0;
    for (int t = 0; t < ntiles; ++t) {
        const int kt = t * 64;
        const bool pf = (t + 1 < ntiles);
        bf16x8 vA, vB;
        if (pf) { stageK(cur ^ 1, kt + 64); vload(kt + 64, vA, vB); }

        // ---- scores: S^T[key][q] = K.Q (3-term split) ----
        const int kbase = cur * 8192;
        f32x4 sacc[4] = {};
        #pragma unroll
        for (int c = 0; c < 2; ++c)
            #pragma unroll
            for (int t4 = 0; t4 < 4; ++t4) {
                const int krow = t4 * 16 + col;
                bf16x8 kh = *(const bf16x8*)&lds[kbase + SWZ(krow, c * 32 + oct)];
                bf16x8 kl = *(const bf16x8*)&lds[kbase + 4096 + SWZ(krow, c * 32 + oct)];
                sacc[t4] = mfma_bf16(kh, qfh[c], sacc[t4]);
                sacc[t4] = mfma_bf16(kh, qfl[c], sacc[t4]);
                sacc[t4] = mfma_bf16(kl, qfh[c], sacc[t4]);
            }

        // ---- softmax (lane-local per q=col) ----
        float p[16];
        float mx = -INFINITY;
        if (t == ntiles - 1) {   // diagonal tile: mask (logit ~0)
            #pragma unroll
            for (int t4 = 0; t4 < 4; ++t4)
                #pragma unroll
                for (int r = 0; r < 4; ++r) {
                    float s = sacc[t4][r] * 0.125f;
                    if (kt + t4 * 16 + g * 4 + r > qg) s = 0.0f;
                    p[t4 * 4 + r] = s; mx = fmaxf(mx, s);
                }
        } else {
            #pragma unroll
            for (int t4 = 0; t4 < 4; ++t4)
                #pragma unroll
                for (int r = 0; r < 4; ++r) {
                    float s = sacc[t4][r] * 0.125f;
                    p[t4 * 4 + r] = s; mx = fmaxf(mx, s);
                }
        }
        mx = fmaxf(mx, __shfl_xor(mx, 16));
        mx = fmaxf(mx, __shfl_xor(mx, 32));
        const float mnew = fmaxf(m_run, mx);
        const float corr = __expf(m_run - mnew);
        float ls = 0.f;
        unsigned short* Pw = &lds[24576 + w * 1024];
        #pragma unroll
        for (int t4 = 0; t4 < 4; ++t4)
            #pragma unroll
            for (int rp = 0; rp < 2; ++rp) {
                float e0 = __expf(p[t4 * 4 + rp * 2] - mnew);
                float e1 = __expf(p[t4 * 4 + rp * 2 + 1] - mnew);
                ls += e0 + e1;
                bf16x2 pk; pk[0] = (__bf16)e0; pk[1] = (__bf16)e1;
                *(bf16x2*)&Pw[SWZ(col, t4 * 16 + g * 4 + rp * 2)] = pk;
            }
        ls += __shfl_xor(ls, 16);
        ls += __shfl_xor(ls, 32);
        l_run = l_run * corr + ls;
        m_run = mnew;

        __builtin_amdgcn_wave_barrier();

        // ---- PV: O^T[d][q] += Vt . P (1-term) ----
        #pragma unroll
        for (int dt = 0; dt < 4; ++dt) {
            oacc[dt][0] *= corr; oacc[dt][1] *= corr;
            oacc[dt][2] *= corr; oacc[dt][3] *= corr;
        }
        const int vbase = 16384 + cur * 4096;
        #pragma unroll
        for (int c = 0; c < 2; ++c) {
            bf16x8 pfv = *(const bf16x8*)&Pw[SWZ(col, c * 32 + oct)];
            #pragma unroll
            for (int dt = 0; dt < 4; ++dt) {
                bf16x8 vh = *(const bf16x8*)&lds[vbase + SWZ(dt * 16 + col, c * 32 + oct)];
                oacc[dt] = mfma_bf16(vh, pfv, oacc[dt]);
            }
        }

        if (pf) vwrite(cur ^ 1, vA, vB);
        __syncthreads();
        cur ^= 1;
    }

    // ---- masked tail: weight exp(-m) per key, exact fp32 V suffix sum ----
    {
        const float wt = __expf(-m_run);
        l_run += (float)(S_ - q0 - 64) * wt;
        const float* vs = vsuf + ((size_t)h * 33 + (q0idx + 1)) * 64;
        #pragma unroll
        for (int dt = 0; dt < 4; ++dt)
            #pragma unroll
            for (int r = 0; r < 4; ++r)
                oacc[dt][r] += wt * vs[dt * 16 + g * 4 + r];
    }

    // ---- epilogue: normalize, per-wave transpose, hi/lo pre-swizzled store ----
    const float inv = 1.f / l_run;
    float* ow = (float*)&lds[w * 4096];   // 8KB per-wave scratch ([16][40] f32)
    const int q = lane >> 2, jj = lane & 3;
    #pragma unroll
    for (int half = 0; half < 2; ++half) {
        __builtin_amdgcn_wave_barrier();
        #pragma unroll
        for (int t4 = 0; t4 < 2; ++t4)
            #pragma unroll
            for (int r = 0; r < 4; ++r)
                ow[col * 40 + t4 * 16 + g * 4 + r] = oacc[half * 2 + t4][r] * inv;
        __builtin_amdgcn_wave_barrier();
        f32x4 v0 = *(const f32x4*)&ow[q * 40 + jj * 8];
        f32x4 v1 = *(const f32x4*)&ow[q * 40 + jj * 8 + 4];
        ushort8 hi, lo;
        split2x4(v0, v1, hi, lo);
        const int m = brow + q0 + w * 16 + q;
        const int chunk = (half * 4 + jj) ^ (m & 7);
        const size_t off = (size_t)m * 1024 + h * 64 + chunk * 8;
        *(ushort8*)&ohi[off] = hi;
        *(ushort8*)&olo[off] = lo;
    }
}

// ---------------------------------------------------------------------------
extern "C" void kernel_launch(void* const* d_in, const int* in_sizes, int n_in,
                              void* d_out, int out_size, void* d_ws, size_t ws_size,
                              hipStream_t stream) {
    const float* x     = (const float*)d_in[0];   // [B,S,D]
    const float* W_qkv = (const float*)d_in[1];   // [D,3D]
    const float* b_qkv = (const float*)d_in[2];   // [3D]
    const float* W_out = (const float*)d_in[3];   // [D,D]
    const float* b_out = (const float*)d_in[4];   // [D]
    float* out = (float*)d_out;                   // [B,S,D]

    // ws layout, 58.99 MB total (proven footprint was 67.3 MB in r3):
    unsigned short* us  = (unsigned short*)d_ws;
    unsigned short* Wqh = us;                                  // [3072][1024]
    unsigned short* Wql = Wqh + (size_t)3072 * 1024;
    unsigned short* Woh = Wql + (size_t)3072 * 1024;           // [1024][1024]
    unsigned short* Wol = Woh + (size_t)1024 * 1024;
    unsigned short* XAhi = Wol + (size_t)1024 * 1024;          // [4096][1024] X, then attn-out
    unsigned short* XAlo = XAhi + (size_t)4096 * 1024;
    unsigned short* QKVh = XAlo + (size_t)4096 * 1024;         // [2048][3072] per batch
    unsigned short* QKVl = QKVh + (size_t)2048 * 3072;
    float* tsum = (float*)(QKVl + (size_t)2048 * 3072);        // [16][32][64]
    float* vsuf = tsum + (size_t)16 * 32 * 64;                 // [16][33][64]

    conv_wt_kernel<<<dim3(16, 48), 256, 0, stream>>>(W_qkv, 3072, Wqh, Wql);
    conv_wt_kernel<<<dim3(16, 16), 256, 0, stream>>>(W_out, 1024, Woh, Wol);
    conv_rows_kernel<<<dim3(2048), 256, 0, stream>>>(x, XAhi, XAlo);

    for (int b = 0; b < 2; ++b) {
        gemm_mfma_kernel<1><<<dim3(24, 16), 256, 0, stream>>>(
            XAhi + (size_t)b * 2048 * 1024, XAlo + (size_t)b * 2048 * 1024,
            Wqh, Wql, b_qkv, nullptr, QKVh, QKVl, 2048, 3072, 1024);
        vsuf_part_kernel<<<dim3(16, 8), 256, 0, stream>>>(QKVh, QKVl, tsum);
        vsuf_scan_kernel<<<dim3(16), 64, 0, stream>>>(tsum, vsuf);
        // attn writes rows b*2048.. of XA (aliases X; batch-1 X rows untouched)
        attn_kernel<<<dim3(32, 16), 256, 0, stream>>>(
            QKVh, QKVl, vsuf, XAhi, XAlo, b * 2048);
    }

    gemm_mfma_kernel<0><<<dim3(8, 32), 256, 0, stream>>>(
        XAhi, XAlo, Woh, Wol, b_out, out, nullptr, nullptr, 4096, 1024, 1024);
}

// Round 5
// 232.893 us; speedup vs baseline: 5.5224x; 1.1159x over previous
//
#include <hip/hip_runtime.h>
#include <math.h>

// Problem constants (reference: B=2, S=2048, D=1024, H=16, HD=64)
#define B_ 2
#define S_ 2048
#define D_ 1024
#define H_ 16
#define HD_ 64

typedef unsigned short ushort8 __attribute__((ext_vector_type(8)));
typedef __bf16 bf16x8 __attribute__((ext_vector_type(8)));
typedef __bf16 bf16x2 __attribute__((ext_vector_type(2)));
typedef float f32x4 __attribute__((ext_vector_type(4)));

__device__ __forceinline__ unsigned short f2bf(float f) {
    union { __bf16 b; unsigned short u; } v;
    v.b = (__bf16)f;                       // native v_cvt, RNE
    return v.u;
}
__device__ __forceinline__ float bf2f(unsigned short u) {
    union { unsigned short u; __bf16 b; } v; v.u = u;
    return (float)v.b;
}
__device__ __forceinline__ void split2x4(f32x4 a, f32x4 b, ushort8& hi, ushort8& lo) {
    #pragma unroll
    for (int i = 0; i < 4; ++i) {
        unsigned short h = f2bf(a[i]); hi[i] = h; lo[i] = f2bf(a[i] - bf2f(h));
    }
    #pragma unroll
    for (int i = 0; i < 4; ++i) {
        unsigned short h = f2bf(b[i]); hi[4 + i] = h; lo[4 + i] = f2bf(b[i] - bf2f(h));
    }
}

// XOR swizzle for [R][64] bf16 tiles (128B rows): in-row 16B-chunk permute by row&7.
#define SWZ(row, col) ((((row)) << 6) + (((col)) ^ ((((row)) & 7) << 3)))

__device__ __forceinline__ f32x4 mfma_bf16(bf16x8 a, bf16x8 b, f32x4 c) {
    return __builtin_amdgcn_mfma_f32_16x16x32_bf16(a, b, c, 0, 0, 0);
}

typedef __attribute__((address_space(1))) const void gvoid_t;
typedef __attribute__((address_space(3))) void lvoid_t;
__device__ __forceinline__ void gload_lds16(const void* g, void* l) {
    __builtin_amdgcn_global_load_lds((gvoid_t*)g, (lvoid_t*)l, 16, 0, 0);
}

// ---------------------------------------------------------------------------
// conv_rows: fp32 [4096][1024] -> hi/lo bf16, pre-swizzled chunks (key = row&7)
// ---------------------------------------------------------------------------
__global__ __launch_bounds__(256) void conv_rows_kernel(
    const float* __restrict__ in, unsigned short* __restrict__ ohi,
    unsigned short* __restrict__ olo)
{
    const int id = blockIdx.x * 256 + threadIdx.x;   // [0, 4096*128)
    const int r = id >> 7, c = id & 127;
    const float* s = in + (size_t)r * 1024 + c * 8;
    f32x4 v0 = *(const f32x4*)s, v1 = *(const f32x4*)(s + 4);
    ushort8 hi, lo;
    split2x4(v0, v1, hi, lo);
    const int oc = (c & ~7) | ((c ^ r) & 7);
    *(ushort8*)&ohi[(size_t)r * 1024 + oc * 8] = hi;
    *(ushort8*)&olo[(size_t)r * 1024 + oc * 8] = lo;
}

// ---------------------------------------------------------------------------
// conv_wt: W fp32 [1024 k][ldw] -> Wt hi/lo bf16 [N][1024], transposed +
// pre-swizzled (key = n&7). Grid (K/64, N/64).
// ---------------------------------------------------------------------------
__global__ __launch_bounds__(256) void conv_wt_kernel(
    const float* __restrict__ W, int ldw,
    unsigned short* __restrict__ othi, unsigned short* __restrict__ otlo)
{
    __shared__ float T[64][65];
    const int tid = threadIdx.x;
    const int kx = blockIdx.x * 64, ny = blockIdx.y * 64;
    const int kl = tid >> 2, c0 = (tid & 3) * 16;
    const float* s = W + (size_t)(kx + kl) * ldw + ny + c0;
    #pragma unroll
    for (int i = 0; i < 4; ++i) *(f32x4*)&T[kl][c0 + 4 * i] = *(const f32x4*)(s + 4 * i);
    __syncthreads();
    const int nl = tid >> 2, jj = (tid & 3) * 2;
    #pragma unroll
    for (int p = 0; p < 2; ++p) {
        const int j = jj + p;
        f32x4 a, b;
        #pragma unroll
        for (int i = 0; i < 4; ++i) a[i] = T[j * 8 + i][nl];
        #pragma unroll
        for (int i = 0; i < 4; ++i) b[i] = T[j * 8 + 4 + i][nl];
        ushort8 hi, lo;
        split2x4(a, b, hi, lo);
        const int row = ny + nl;
        const int chunk = blockIdx.x * 8 + (j ^ (nl & 7));
        *(ushort8*)&othi[(size_t)row * 1024 + chunk * 8] = hi;
        *(ushort8*)&otlo[(size_t)row * 1024 + chunk * 8] = lo;
    }
}

// ---------------------------------------------------------------------------
// Split-bf16 MFMA GEMM: C[M,N] = A[M,K] @ Bt[N,K]^T + bias. (validated r2-r4)
// ---------------------------------------------------------------------------
template<int OUTMODE>
__global__ __launch_bounds__(256) void gemm_mfma_kernel(
    const unsigned short* __restrict__ Ahi, const unsigned short* __restrict__ Alo,
    const unsigned short* __restrict__ Bthi, const unsigned short* __restrict__ Btlo,
    const float* __restrict__ bias, float* __restrict__ Cf,
    unsigned short* __restrict__ Ohi, unsigned short* __restrict__ Olo,
    int M, int N, int K)
{
    __shared__ __align__(16) unsigned short lds[4 * 8192];   // Ahi|Alo|Bhi|Blo [128][64]
    const int tid = threadIdx.x, lane = tid & 63, w = tid >> 6;
    const int wm = w >> 1, wn = w & 1;
    const int m0 = blockIdx.y * 128, n0 = blockIdx.x * 128;
    const int col = lane & 15, oct = (lane >> 4) * 8;
    const int srow = lane >> 3, scol = (lane & 7) * 8;

    f32x4 acc[4][4] = {};

    for (int kt = 0; kt < K; kt += 64) {
        __syncthreads();
        #pragma unroll
        for (int j = 0; j < 4; ++j) {
            const int cc = w * 4 + j;
            const int row = cc * 8 + srow;
            const size_t aoff = (size_t)(m0 + row) * K + kt + scol;
            const size_t boff = (size_t)(n0 + row) * K + kt + scol;
            gload_lds16(Ahi + aoff,  &lds[0 * 8192 + cc * 512]);
            gload_lds16(Alo + aoff,  &lds[1 * 8192 + cc * 512]);
            gload_lds16(Bthi + boff, &lds[2 * 8192 + cc * 512]);
            gload_lds16(Btlo + boff, &lds[3 * 8192 + cc * 512]);
        }
        __syncthreads();
        #pragma unroll
        for (int kh = 0; kh < 2; ++kh) {
            bf16x8 ah[4], al[4], bh[4], bl[4];
            #pragma unroll
            for (int i = 0; i < 4; ++i) {
                const int ar = wm * 64 + i * 16 + col;
                const int br = wn * 64 + i * 16 + col;
                const int c = kh * 32 + oct;
                ah[i] = *(const bf16x8*)&lds[0 * 8192 + SWZ(ar, c)];
                al[i] = *(const bf16x8*)&lds[1 * 8192 + SWZ(ar, c)];
                bh[i] = *(const bf16x8*)&lds[2 * 8192 + SWZ(br, c)];
                bl[i] = *(const bf16x8*)&lds[3 * 8192 + SWZ(br, c)];
            }
            #pragma unroll
            for (int mi = 0; mi < 4; ++mi)
                #pragma unroll
                for (int nj = 0; nj < 4; ++nj) {
                    acc[mi][nj] = mfma_bf16(ah[mi], bh[nj], acc[mi][nj]);
                    acc[mi][nj] = mfma_bf16(ah[mi], bl[nj], acc[mi][nj]);
                    acc[mi][nj] = mfma_bf16(al[mi], bh[nj], acc[mi][nj]);
                }
        }
    }

    __syncthreads();
    float* ow = (float*)&lds[w * 8192];   // [64][64] fp32 per wave
    #pragma unroll
    for (int mi = 0; mi < 4; ++mi)
        #pragma unroll
        for (int nj = 0; nj < 4; ++nj)
            #pragma unroll
            for (int r = 0; r < 4; ++r)
                ow[(mi * 16 + (lane >> 4) * 4 + r) * 64 + nj * 16 + col] = acc[mi][nj][r];
    __builtin_amdgcn_wave_barrier();

    const int nc = (lane & 7) * 8;
    const int nabs = n0 + wn * 64 + nc;
    f32x4 bi0 = *(const f32x4*)&bias[nabs];
    f32x4 bi1 = *(const f32x4*)&bias[nabs + 4];
    #pragma unroll
    for (int it = 0; it < 8; ++it) {
        const int rl = it * 8 + (lane >> 3);
        f32x4 v0 = *(const f32x4*)&ow[rl * 64 + nc];
        f32x4 v1 = *(const f32x4*)&ow[rl * 64 + nc + 4];
        v0 += bi0; v1 += bi1;
        const int m = m0 + wm * 64 + rl;
        if (OUTMODE == 0) {
            *(f32x4*)&Cf[(size_t)m * N + nabs] = v0;
            *(f32x4*)&Cf[(size_t)m * N + nabs + 4] = v1;
        } else {
            ushort8 hi, lo;
            split2x4(v0, v1, hi, lo);
            const int chunk = (lane & 7) ^ (m & 7);
            const size_t off = (size_t)m * N + n0 + wn * 64 + chunk * 8;
            *(ushort8*)&Ohi[off] = hi;
            *(ushort8*)&Olo[off] = lo;
        }
    }
}

// ---------------------------------------------------------------------------
// V suffix tile sums (vectorized): tsum[h][t][d] = sum_{k in tile t} V[k][d]
// ---------------------------------------------------------------------------
__global__ __launch_bounds__(256) void vsuf_part_kernel(
    const unsigned short* __restrict__ qh, const unsigned short* __restrict__ ql,
    float* __restrict__ tsum)
{
    const int h = blockIdx.x, tg = blockIdx.y;    // grid (16, 8)
    const int tl = threadIdx.x >> 6, lane = threadIdx.x & 63;
    const int t = tg * 4 + tl;
    const int dgrp = lane & 7, rr = lane >> 3;
    const int colbase = h * 192 + 128;
    float sacc[8] = {};
    for (int kk = 0; kk < 8; ++kk) {
        const int row = t * 64 + rr + kk * 8;
        const size_t off = (size_t)row * 3072 + colbase + ((dgrp ^ rr) << 3);
        ushort8 vh = *(const ushort8*)&qh[off];
        ushort8 vl = *(const ushort8*)&ql[off];
        #pragma unroll
        for (int e = 0; e < 8; ++e) sacc[e] += bf2f(vh[e]) + bf2f(vl[e]);
    }
    #pragma unroll
    for (int off = 8; off < 64; off <<= 1)
        #pragma unroll
        for (int e = 0; e < 8; ++e) sacc[e] += __shfl_xor(sacc[e], off);
    if (rr == 0) {
        float* dst = &tsum[((size_t)h * 32 + t) * 64 + dgrp * 8];
        f32x4 v0, v1;
        #pragma unroll
        for (int e = 0; e < 4; ++e) { v0[e] = sacc[e]; v1[e] = sacc[4 + e]; }
        *(f32x4*)dst = v0;
        *(f32x4*)(dst + 4) = v1;
    }
}

__global__ __launch_bounds__(64) void vsuf_scan_kernel(
    const float* __restrict__ tsum, float* __restrict__ vsuf)
{
    const int h = blockIdx.x, d = threadIdx.x;    // 16 blocks x 64 thr
    float acc = 0.f;
    vsuf[((size_t)h * 33 + 32) * 64 + d] = 0.f;
    for (int t = 31; t >= 0; --t) {
        acc += tsum[((size_t)h * 32 + t) * 64 + d];
        vsuf[((size_t)h * 33 + t) * 64 + d] = acc;
    }
}

// ---------------------------------------------------------------------------
// Causal-skip MFMA flash attention with key-range segmentation.
// jobs 0..9: direct q-tile i=job (<=10 K-tiles, exact masked-tail via vsuf).
// jobs 10..67: segment s of q-tile i>=10 (<=10 K-tiles), writes fp32 partial
//   (O^T, m, l) into partO/partML (scratch in d_out); combined later.
// Single-buffer K(32KB LDS total), reg-staged K/V (T14), 2 barriers/tile,
// 4 blocks/CU. Mask semantics faithful (masked logit -9e-13 == 0 in fp32).
// ---------------------------------------------------------------------------
__global__ __launch_bounds__(256, 4) void attn_kernel(
    const unsigned short* __restrict__ qh, const unsigned short* __restrict__ ql,
    const float* __restrict__ vsuf,
    unsigned short* __restrict__ ohi, unsigned short* __restrict__ olo,
    float* __restrict__ partO, float* __restrict__ partML,
    int brow)
{
    __shared__ __align__(16) unsigned short lds[16384];   // 32 KB
    // [0,4096): K-hi  [4096,8192): K-lo  [8192,12288): Vt-hi  [12288,16384): Ps
    // Q staging aliases [0,8192) before the main loop.

    const int tid = threadIdx.x, lane = tid & 63, w = tid >> 6;
    const int g = lane >> 4, oct = g * 8, col = lane & 15;
    const int h = blockIdx.y;
    const int kp = tid & 31, dg = tid >> 5;

    // ---- job decode ----
    const int job = blockIdx.x;
    int i = job, s = 0, slot = -1;
    if (job >= 10) {
        int r = job - 10, cum = 0;
        for (int ii = 10; ii < 32; ++ii) {
            const int ns = (ii + 10) / 10;          // ceil((ii+1)/10)
            if (r < cum + ns) { i = ii; s = r - cum; break; }
            cum += ns;
        }
        slot = (size_t)0 + h * 58 + (job - 10);
    }
    const int q0 = i * 64;
    const int ntile_all = i + 1;
    const int t_begin = s * 10;
    const int t_end = (slot < 0) ? ntile_all : min(t_begin + 10, ntile_all);
    const bool isseg = (slot >= 0);

    auto kissue = [&](int ktbase, ushort8* kr) {
        #pragma unroll
        for (int j = 0; j < 4; ++j) {
            const int cc = w * 4 + j;
            const unsigned short* src = (cc < 8) ? qh : ql;
            const int row = ktbase + (cc & 7) * 8 + (lane >> 3);
            kr[j] = *(const ushort8*)(src + (size_t)row * 3072 + h * 192 + 64 + (lane & 7) * 8);
        }
    };
    auto kwrite = [&](const ushort8* kr) {
        #pragma unroll
        for (int j = 0; j < 4; ++j) {
            const int cc = w * 4 + j;
            *(ushort8*)&lds[(cc < 8 ? 0 : 4096) + (cc & 7) * 512 + lane * 8] = kr[j];
        }
    };
    auto vload = [&](int ktbase, bf16x8& vA, bf16x8& vB) {
        const int r0 = ktbase + 2 * kp, r1 = r0 + 1;
        const int pA = dg ^ (r0 & 7), pB = dg ^ (r1 & 7);
        vA = *(const bf16x8*)&qh[(size_t)r0 * 3072 + h * 192 + 128 + pA * 8];
        vB = *(const bf16x8*)&qh[(size_t)r1 * 3072 + h * 192 + 128 + pB * 8];
    };
    auto vwrite = [&](bf16x8 vA, bf16x8 vB) {
        #pragma unroll
        for (int e = 0; e < 8; ++e) {
            const int d = dg * 8 + e;
            bf16x2 pr; pr[0] = vA[e]; pr[1] = vB[e];
            *(bf16x2*)&lds[8192 + SWZ(d, 2 * kp)] = pr;
        }
    };

    // ---- stage Q tile (pre-swizzled global -> linear LDS, aliases K region) ----
    #pragma unroll
    for (int j = 0; j < 4; ++j) {
        const int cc = w * 4 + j;
        const unsigned short* src = (cc < 8) ? qh : ql;
        const int c7 = cc & 7;
        const int row = q0 + c7 * 8 + (lane >> 3);
        gload_lds16(src + (size_t)row * 3072 + h * 192 + (lane & 7) * 8,
                    &lds[(cc < 8 ? 0 : 4096) + c7 * 512]);
    }
    // early-issue first K/V tile into regs (independent of Q staging)
    ushort8 kr[4]; bf16x8 vA, vB;
    kissue(t_begin * 64, kr);
    vload(t_begin * 64, vA, vB);
    __syncthreads();
    bf16x8 qfh[2], qfl[2];
    {
        const int qrow = w * 16 + col;
        qfh[0] = *(const bf16x8*)&lds[SWZ(qrow, oct)];
        qfh[1] = *(const bf16x8*)&lds[SWZ(qrow, 32 + oct)];
        qfl[0] = *(const bf16x8*)&lds[4096 + SWZ(qrow, oct)];
        qfl[1] = *(const bf16x8*)&lds[4096 + SWZ(qrow, 32 + oct)];
    }
    __syncthreads();
    kwrite(kr);
    vwrite(vA, vB);
    __syncthreads();

    const int qg = q0 + w * 16 + col;
    float m_run = isseg ? -INFINITY : 0.f;   // direct: masked-logit 0 joins max
    float l_run = 0.f;
    f32x4 oacc[4] = {};

    for (int t = t_begin; t < t_end; ++t) {
        const int kt = t * 64;
        const bool pf = (t + 1 < t_end);
        if (pf) { kissue(kt + 64, kr); vload(kt + 64, vA, vB); }

        // ---- scores: S^T[key][q] = K.Q (3-term split) ----
        f32x4 sacc[4] = {};
        #pragma unroll
        for (int c = 0; c < 2; ++c)
            #pragma unroll
            for (int t4 = 0; t4 < 4; ++t4) {
                const int krow = t4 * 16 + col;
                bf16x8 kh = *(const bf16x8*)&lds[SWZ(krow, c * 32 + oct)];
                bf16x8 kl = *(const bf16x8*)&lds[4096 + SWZ(krow, c * 32 + oct)];
                sacc[t4] = mfma_bf16(kh, qfh[c], sacc[t4]);
                sacc[t4] = mfma_bf16(kh, qfl[c], sacc[t4]);
                sacc[t4] = mfma_bf16(kl, qfh[c], sacc[t4]);
            }

        // ---- softmax (lane-local per q=col) ----
        float p[16];
        float mx = -INFINITY;
        if (t == ntile_all - 1) {   // diagonal tile: masked logit ~0
            #pragma unroll
            for (int t4 = 0; t4 < 4; ++t4)
                #pragma unroll
                for (int r = 0; r < 4; ++r) {
                    float sv = sacc[t4][r] * 0.125f;
                    if (kt + t4 * 16 + g * 4 + r > qg) sv = 0.0f;
                    p[t4 * 4 + r] = sv; mx = fmaxf(mx, sv);
                }
        } else {
            #pragma unroll
            for (int t4 = 0; t4 < 4; ++t4)
                #pragma unroll
                for (int r = 0; r < 4; ++r) {
                    float sv = sacc[t4][r] * 0.125f;
                    p[t4 * 4 + r] = sv; mx = fmaxf(mx, sv);
                }
        }
        mx = fmaxf(mx, __shfl_xor(mx, 16));
        mx = fmaxf(mx, __shfl_xor(mx, 32));
        const float mnew = fmaxf(m_run, mx);
        const float corr = __expf(m_run - mnew);
        float ls = 0.f;
        unsigned short* Pw = &lds[12288 + w * 1024];
        #pragma unroll
        for (int t4 = 0; t4 < 4; ++t4)
            #pragma unroll
            for (int rp = 0; rp < 2; ++rp) {
                float e0 = __expf(p[t4 * 4 + rp * 2] - mnew);
                float e1 = __expf(p[t4 * 4 + rp * 2 + 1] - mnew);
                ls += e0 + e1;
                bf16x2 pk; pk[0] = (__bf16)e0; pk[1] = (__bf16)e1;
                *(bf16x2*)&Pw[SWZ(col, t4 * 16 + g * 4 + rp * 2)] = pk;
            }
        ls += __shfl_xor(ls, 16);
        ls += __shfl_xor(ls, 32);
        l_run = l_run * corr + ls;
        m_run = mnew;

        __syncthreads();                 // (A) all K/Ps readers-writers aligned
        if (pf) kwrite(kr);              // K(t+1) -> LDS (ordered vs QK(t+1) by (B))

        // ---- PV: O^T[d][q] += Vt . P (1-term) ----
        #pragma unroll
        for (int dt = 0; dt < 4; ++dt) {
            oacc[dt][0] *= corr; oacc[dt][1] *= corr;
            oacc[dt][2] *= corr; oacc[dt][3] *= corr;
        }
        #pragma unroll
        for (int c = 0; c < 2; ++c) {
            bf16x8 pfv = *(const bf16x8*)&Pw[SWZ(col, c * 32 + oct)];
            #pragma unroll
            for (int dt = 0; dt < 4; ++dt) {
                bf16x8 vh = *(const bf16x8*)&lds[8192 + SWZ(dt * 16 + col, c * 32 + oct)];
                oacc[dt] = mfma_bf16(vh, pfv, oacc[dt]);
            }
        }

        __syncthreads();                 // (B) all V readers done
        if (pf) vwrite(vA, vB);          // V(t+1) -> LDS (ordered vs PV(t+1) by (A))
    }

    if (isseg) {
        // ---- write fp32 partial (O^T, m, l) ----
        float* po = partO + (size_t)slot * 4096;
        #pragma unroll
        for (int dt = 0; dt < 4; ++dt)
            #pragma unroll
            for (int r = 0; r < 4; ++r)
                po[(dt * 16 + g * 4 + r) * 64 + w * 16 + col] = oacc[dt][r];
        if (g == 0) {
            partML[(size_t)slot * 128 + w * 16 + col] = m_run;
            partML[(size_t)slot * 128 + 64 + w * 16 + col] = l_run;
        }
        return;
    }

    // ---- direct path: masked tail (exact) + normalize + store ----
    {
        const float wt = __expf(-m_run);
        l_run += (float)(S_ - q0 - 64) * wt;
        const float* vs = vsuf + ((size_t)h * 33 + (i + 1)) * 64;
        #pragma unroll
        for (int dt = 0; dt < 4; ++dt)
            #pragma unroll
            for (int r = 0; r < 4; ++r)
                oacc[dt][r] += wt * vs[dt * 16 + g * 4 + r];
    }
    const float inv = 1.f / l_run;
    float* ow = (float*)&lds[w * 4096];   // 8KB-byte stride per wave
    const int q = lane >> 2, jj = lane & 3;
    #pragma unroll
    for (int half = 0; half < 2; ++half) {
        __builtin_amdgcn_wave_barrier();
        #pragma unroll
        for (int t4 = 0; t4 < 2; ++t4)
            #pragma unroll
            for (int r = 0; r < 4; ++r)
                ow[col * 40 + t4 * 16 + g * 4 + r] = oacc[half * 2 + t4][r] * inv;
        __builtin_amdgcn_wave_barrier();
        f32x4 v0 = *(const f32x4*)&ow[q * 40 + jj * 8];
        f32x4 v1 = *(const f32x4*)&ow[q * 40 + jj * 8 + 4];
        ushort8 hi, lo;
        split2x4(v0, v1, hi, lo);
        const int m = brow + q0 + w * 16 + q;
        const int chunk = (half * 4 + jj) ^ (m & 7);
        const size_t off = (size_t)m * 1024 + h * 64 + chunk * 8;
        *(ushort8*)&ohi[off] = hi;
        *(ushort8*)&olo[off] = lo;
    }
}

// ---------------------------------------------------------------------------
// Combine partials for split q-tiles (i>=10): O = (sum_s e^{m_s-m*} O_s +
// e^{-m*} vsuf) / l*, with l* = sum_s l_s e^{m_s-m*} + tailcount e^{-m*}.
// m* includes the masked logit 0. Exactly the same math as the direct path.
// ---------------------------------------------------------------------------
__global__ __launch_bounds__(256) void attn_combine_kernel(
    const float* __restrict__ partO, const float* __restrict__ partML,
    const float* __restrict__ vsuf,
    unsigned short* __restrict__ ohi, unsigned short* __restrict__ olo,
    int brow)
{
    const int i = 10 + blockIdx.x;              // q-tile 10..31
    const int h = blockIdx.y;
    const int nseg = (i + 10) / 10;             // ceil((i+1)/10)
    int cum = 0;
    for (int j = 10; j < i; ++j) cum += (j + 10) / 10;
    const int slot0 = h * 58 + cum;
    const int q = threadIdx.x & 63, dgrp = threadIdx.x >> 6;
    const int q0 = i * 64;

    float mstar = 0.f;                          // masked logit 0 joins the max
    for (int sg = 0; sg < nseg; ++sg)
        mstar = fmaxf(mstar, partML[(size_t)(slot0 + sg) * 128 + q]);
    const float wtail = __expf(-mstar);
    float lstar = (float)(S_ - q0 - 64) * wtail;

    float od[16];
    const float* vs = vsuf + ((size_t)h * 33 + i + 1) * 64 + dgrp * 16;
    #pragma unroll
    for (int k = 0; k < 16; ++k) od[k] = wtail * vs[k];

    for (int sg = 0; sg < nseg; ++sg) {
        const float ms = partML[(size_t)(slot0 + sg) * 128 + q];
        const float lsv = partML[(size_t)(slot0 + sg) * 128 + 64 + q];
        const float wv = __expf(ms - mstar);
        lstar += lsv * wv;
        const float* po = partO + (size_t)(slot0 + sg) * 4096 + (size_t)(dgrp * 16) * 64 + q;
        #pragma unroll
        for (int k = 0; k < 16; ++k) od[k] += wv * po[k * 64];
    }

    const float inv = 1.f / lstar;
    f32x4 a0, a1, b0, b1;
    #pragma unroll
    for (int k = 0; k < 4; ++k) {
        a0[k] = od[k] * inv; a1[k] = od[4 + k] * inv;
        b0[k] = od[8 + k] * inv; b1[k] = od[12 + k] * inv;
    }
    ushort8 hi0, lo0, hi1, lo1;
    split2x4(a0, a1, hi0, lo0);
    split2x4(b0, b1, hi1, lo1);
    const int mrow = brow + q0 + q;
    const int c0 = (dgrp * 2) ^ (mrow & 7);
    const int c1 = (dgrp * 2 + 1) ^ (mrow & 7);
    const size_t base = (size_t)mrow * 1024 + h * 64;
    *(ushort8*)&ohi[base + c0 * 8] = hi0;
    *(ushort8*)&olo[base + c0 * 8] = lo0;
    *(ushort8*)&ohi[base + c1 * 8] = hi1;
    *(ushort8*)&olo[base + c1 * 8] = lo1;
}

// ---------------------------------------------------------------------------
extern "C" void kernel_launch(void* const* d_in, const int* in_sizes, int n_in,
                              void* d_out, int out_size, void* d_ws, size_t ws_size,
                              hipStream_t stream) {
    const float* x     = (const float*)d_in[0];   // [B,S,D]
    const float* W_qkv = (const float*)d_in[1];   // [D,3D]
    const float* b_qkv = (const float*)d_in[2];   // [3D]
    const float* W_out = (const float*)d_in[3];   // [D,D]
    const float* b_out = (const float*)d_in[4];   // [D]
    float* out = (float*)d_out;                   // [B,S,D]

    // ws layout (59.0 MB, proven footprint 67.3 MB in r2):
    unsigned short* us  = (unsigned short*)d_ws;
    unsigned short* Wqh = us;                                  // [3072][1024]
    unsigned short* Wql = Wqh + (size_t)3072 * 1024;
    unsigned short* Woh = Wql + (size_t)3072 * 1024;           // [1024][1024]
    unsigned short* Wol = Woh + (size_t)1024 * 1024;
    unsigned short* XAhi = Wol + (size_t)1024 * 1024;          // [4096][1024] X, then attn-out
    unsigned short* XAlo = XAhi + (size_t)4096 * 1024;
    unsigned short* QKVh = XAlo + (size_t)4096 * 1024;         // [2048][3072] per batch
    unsigned short* QKVl = QKVh + (size_t)2048 * 3072;
    float* tsum = (float*)(QKVl + (size_t)2048 * 3072);        // [16][32][64]
    float* vsuf = tsum + (size_t)16 * 32 * 64;                 // [16][33][64]

    // partial scratch inside d_out (overwritten by the final GEMM):
    // 928 slots x (O^T 64x64 f32 + m,l 2x64 f32) = 15.7 MB <= 16.78 MB
    float* partO  = out;                                       // [928][4096]
    float* partML = out + (size_t)928 * 4096;                  // [928][128]

    conv_wt_kernel<<<dim3(16, 48), 256, 0, stream>>>(W_qkv, 3072, Wqh, Wql);
    conv_wt_kernel<<<dim3(16, 16), 256, 0, stream>>>(W_out, 1024, Woh, Wol);
    conv_rows_kernel<<<dim3(2048), 256, 0, stream>>>(x, XAhi, XAlo);

    for (int b = 0; b < 2; ++b) {
        gemm_mfma_kernel<1><<<dim3(24, 16), 256, 0, stream>>>(
            XAhi + (size_t)b * 2048 * 1024, XAlo + (size_t)b * 2048 * 1024,
            Wqh, Wql, b_qkv, nullptr, QKVh, QKVl, 2048, 3072, 1024);
        vsuf_part_kernel<<<dim3(16, 8), 256, 0, stream>>>(QKVh, QKVl, tsum);
        vsuf_scan_kernel<<<dim3(16), 64, 0, stream>>>(tsum, vsuf);
        attn_kernel<<<dim3(68, 16), 256, 0, stream>>>(
            QKVh, QKVl, vsuf, XAhi, XAlo, partO, partML, b * 2048);
        attn_combine_kernel<<<dim3(22, 16), 256, 0, stream>>>(
            partO, partML, vsuf, XAhi, XAlo, b * 2048);
    }

    gemm_mfma_kernel<0><<<dim3(8, 32), 256, 0, stream>>>(
        XAhi, XAlo, Woh, Wol, b_out, out, nullptr, nullptr, 4096, 1024, 1024);
}